// Round 1
// baseline (2055.835 us; speedup 1.0000x reference)
//
#include <hip/hip_runtime.h>
#include <cstddef>
#include <cstdint>

// Problem constants (fixed by reference):
//   B=2, L=4096, D=1024, H=16, hd=64, BH=32, top_u = 4096/5 = 819
constexpr int LSEQ = 4096;
constexpr int DM   = 1024;
constexpr int NH   = 16;
constexpr int HD   = 64;
constexpr int BHT  = 32;     // B*H
constexpr int TOPU = 819;
constexpr int MROWS = 8192;  // B*L

__device__ __forceinline__ float lane_bcast(float v, int l) {
  // wave-uniform lane index -> v_readlane (SALU broadcast, no LDS pipe)
  return __int_as_float(__builtin_amdgcn_readlane(__float_as_int(v), l));
}

// ---------------------------------------------------------------------------
// Y = X @ W^T + bias.  X:[M=8192,1024] row-major, W:[1024,1024] row-major.
// SPLIT_HEADS: write Y[m, n] to Q-layout [(b*16+h), l, d] with
//   b=m>>12, l=m&4095, h=n>>6 (== blockIdx.y since BN=64=hd), d=n&63.
// 64x64 tile, BK=16, 256 threads, 4x4 microtile, fp32.
// ---------------------------------------------------------------------------
template<bool SPLIT_HEADS>
__global__ __launch_bounds__(256) void gemm_xwT(
    const float* __restrict__ X, const float* __restrict__ W,
    const float* __restrict__ bias, float* __restrict__ Y)
{
  __shared__ float As[16][68];   // As[k][m], pad 68 keeps float4 align + no conflicts
  __shared__ float Bs[16][68];   // Bs[k][n]
  const int tid = threadIdx.x;
  const int tx = tid & 15, ty = tid >> 4;
  const int m0 = blockIdx.x * 64, n0 = blockIdx.y * 64;

  const int lr = tid >> 2;          // 0..63 : row within tile
  const int lc = (tid & 3) * 4;     // 0,4,8,12 : k offset
  const float* Xp = X + (size_t)(m0 + lr) * DM + lc;
  const float* Wp = W + (size_t)(n0 + lr) * DM + lc;

  float acc[4][4] = {};

  for (int k0 = 0; k0 < DM; k0 += 16) {
    float4 xv = *reinterpret_cast<const float4*>(Xp + k0);
    float4 wv = *reinterpret_cast<const float4*>(Wp + k0);
    As[lc+0][lr] = xv.x; As[lc+1][lr] = xv.y; As[lc+2][lr] = xv.z; As[lc+3][lr] = xv.w;
    Bs[lc+0][lr] = wv.x; Bs[lc+1][lr] = wv.y; Bs[lc+2][lr] = wv.z; Bs[lc+3][lr] = wv.w;
    __syncthreads();
    #pragma unroll
    for (int kk = 0; kk < 16; ++kk) {
      float a[4], b[4];
      *reinterpret_cast<float4*>(a) = *reinterpret_cast<const float4*>(&As[kk][ty * 4]);
      *reinterpret_cast<float4*>(b) = *reinterpret_cast<const float4*>(&Bs[kk][tx * 4]);
      #pragma unroll
      for (int i = 0; i < 4; ++i)
        #pragma unroll
        for (int j = 0; j < 4; ++j)
          acc[i][j] = fmaf(a[i], b[j], acc[i][j]);
    }
    __syncthreads();
  }

  float bb[4];
  *reinterpret_cast<float4*>(bb) = *reinterpret_cast<const float4*>(bias + n0 + tx * 4);

  #pragma unroll
  for (int i = 0; i < 4; ++i) {
    const int m = m0 + ty * 4 + i;
    float4 o;
    o.x = acc[i][0] + bb[0];
    o.y = acc[i][1] + bb[1];
    o.z = acc[i][2] + bb[2];
    o.w = acc[i][3] + bb[3];
    if (SPLIT_HEADS) {
      const int b = m >> 12, l = m & (LSEQ - 1);
      float* dst = Y + ((size_t)((b << 4) + blockIdx.y) * LSEQ + l) * HD + tx * 4;
      *reinterpret_cast<float4*>(dst) = o;
    } else {
      *reinterpret_cast<float4*>(Y + (size_t)m * DM + n0 + tx * 4) = o;
    }
  }
}

// ---------------------------------------------------------------------------
// Per-bh: squared L2 norms of Q rows, then full bitonic sort (desc value,
// asc index on ties -- matches jax.lax.top_k) of packed (bits<<32)|~idx keys.
// ---------------------------------------------------------------------------
__global__ __launch_bounds__(1024) void topk_kernel(
    const float* __restrict__ Q, int* __restrict__ top_idx)
{
  __shared__ unsigned long long keys[LSEQ];
  const int bh = blockIdx.x;
  const float* Qb = Q + (size_t)bh * LSEQ * HD;

  for (int l = threadIdx.x; l < LSEQ; l += 1024) {
    const float4* row = reinterpret_cast<const float4*>(Qb + (size_t)l * HD);
    float s = 0.f;
    #pragma unroll
    for (int i = 0; i < 16; ++i) {
      float4 v = row[i];
      s += v.x * v.x + v.y * v.y + v.z * v.z + v.w * v.w;
    }
    // s >= 0: float bits are order-preserving as uint
    keys[l] = ((unsigned long long)__float_as_uint(s) << 32) |
              (unsigned long long)(unsigned int)(~l);
  }
  __syncthreads();

  // bitonic sort, descending
  for (int k = 2; k <= LSEQ; k <<= 1) {
    for (int j = k >> 1; j > 0; j >>= 1) {
      for (int t = threadIdx.x; t < LSEQ; t += 1024) {
        const int ixj = t ^ j;
        if (ixj > t) {
          const bool desc = ((t & k) == 0);
          unsigned long long a = keys[t], b = keys[ixj];
          if (desc ? (a < b) : (a > b)) { keys[t] = b; keys[ixj] = a; }
        }
      }
      __syncthreads();
    }
  }

  for (int r = threadIdx.x; r < TOPU; r += 1024)
    top_idx[bh * TOPU + r] = (int)(~(unsigned int)(keys[r] & 0xffffffffu));
}

// ---------------------------------------------------------------------------
// Flash-style attention over selected rows. Block = 4 waves, each wave owns
// 4 query rows; lane = head dim (for Q/acc) or key index (for scores).
// K staged transposed Kc[d][j], V staged Vc[j][d]; stride 65 => conflict-free.
// Broadcasts of per-lane Q/p values via v_readlane (uniform unrolled index).
// Writes O1[b*L + l][h*64 + d] (pre-zeroed).
// ---------------------------------------------------------------------------
__global__ __launch_bounds__(256) void attn_kernel(
    const float* __restrict__ Q, const float* __restrict__ K,
    const float* __restrict__ V, const int* __restrict__ top_idx,
    float* __restrict__ O1)
{
  __shared__ float Kc[64][65];   // Kc[d][j]
  __shared__ float Vc[64][65];   // Vc[j][d]

  const int bh   = blockIdx.y;
  const int tid  = threadIdx.x;
  const int wid  = tid >> 6;
  const int lane = tid & 63;
  const int rbase = blockIdx.x * 16 + wid * 4;
  const float scale = 0.125f;    // 1/sqrt(64)
  const size_t bhL = (size_t)bh * LSEQ;

  float q[4];
  int rowidx[4];
  #pragma unroll
  for (int rr = 0; rr < 4; ++rr) {
    const int r = rbase + rr;
    if (r < TOPU) {
      rowidx[rr] = top_idx[bh * TOPU + r];
      q[rr] = Q[(bhL + rowidx[rr]) * HD + lane] * scale;
    } else {
      rowidx[rr] = -1;
      q[rr] = 0.f;
    }
  }

  float m[4], lsum[4], acc[4];
  #pragma unroll
  for (int rr = 0; rr < 4; ++rr) { m[rr] = -1e30f; lsum[rr] = 0.f; acc[rr] = 0.f; }

  const int jr = tid >> 4;        // 0..15
  const int dc = (tid & 15) * 4;  // 0..60

  for (int c = 0; c < LSEQ / 64; ++c) {
    // stage K (transposed) and V chunks; global reads fully coalesced
    #pragma unroll
    for (int ii = 0; ii < 4; ++ii) {
      const int j = jr + ii * 16;
      const size_t gro = (bhL + c * 64 + j) * HD + dc;
      float4 kv = *reinterpret_cast<const float4*>(K + gro);
      Kc[dc+0][j] = kv.x; Kc[dc+1][j] = kv.y; Kc[dc+2][j] = kv.z; Kc[dc+3][j] = kv.w;
      float4 vv = *reinterpret_cast<const float4*>(V + gro);
      Vc[j][dc+0] = vv.x; Vc[j][dc+1] = vv.y; Vc[j][dc+2] = vv.z; Vc[j][dc+3] = vv.w;
    }
    __syncthreads();

    // scores: lane j holds s[rr] = dot(Qrow_rr, K_j) (already scaled)
    float s[4] = {0.f, 0.f, 0.f, 0.f};
    #pragma unroll
    for (int d = 0; d < 64; ++d) {
      const float kvv = Kc[d][lane];
      #pragma unroll
      for (int rr = 0; rr < 4; ++rr)
        s[rr] = fmaf(lane_bcast(q[rr], d), kvv, s[rr]);
    }

    // online softmax update
    float p[4];
    #pragma unroll
    for (int rr = 0; rr < 4; ++rr) {
      float cm = s[rr];
      #pragma unroll
      for (int off = 32; off; off >>= 1) cm = fmaxf(cm, __shfl_xor(cm, off));
      const float mnew = fmaxf(m[rr], cm);
      const float corr = __expf(m[rr] - mnew);
      p[rr] = __expf(s[rr] - mnew);
      float ps = p[rr];
      #pragma unroll
      for (int off = 32; off; off >>= 1) ps += __shfl_xor(ps, off);
      lsum[rr] = lsum[rr] * corr + ps;
      acc[rr] *= corr;
      m[rr] = mnew;
    }

    // PV: lane d accumulates sum_j p_j * V[j][d]
    #pragma unroll
    for (int j = 0; j < 64; ++j) {
      const float vvv = Vc[j][lane];
      #pragma unroll
      for (int rr = 0; rr < 4; ++rr)
        acc[rr] = fmaf(lane_bcast(p[rr], j), vvv, acc[rr]);
    }
    __syncthreads();
  }

  const int b = bh >> 4, h = bh & 15;
  #pragma unroll
  for (int rr = 0; rr < 4; ++rr) {
    if (rowidx[rr] >= 0) {
      O1[((size_t)(b * LSEQ + rowidx[rr])) * DM + h * HD + lane] = acc[rr] / lsum[rr];
    }
  }
}

// ---------------------------------------------------------------------------
extern "C" void kernel_launch(void* const* d_in, const int* in_sizes, int n_in,
                              void* d_out, int out_size, void* d_ws, size_t ws_size,
                              hipStream_t stream) {
  const float* x  = (const float*)d_in[0];
  const float* Wq = (const float*)d_in[1];
  const float* bq = (const float*)d_in[2];
  const float* Wk = (const float*)d_in[3];
  const float* bk = (const float*)d_in[4];
  const float* Wv = (const float*)d_in[5];
  const float* bv = (const float*)d_in[6];
  const float* Wo = (const float*)d_in[7];
  const float* bo = (const float*)d_in[8];
  float* out = (float*)d_out;

  const size_t QKV = (size_t)BHT * LSEQ * HD;   // 8,388,608 floats = 32 MB
  float* Qb  = (float*)d_ws;
  float* Kb  = Qb + QKV;
  float* Vb  = Kb + QKV;
  float* O1  = Vb + QKV;
  int*   tix = (int*)(O1 + QKV);

  hipMemsetAsync(O1, 0, QKV * sizeof(float), stream);

  const dim3 gg(MROWS / 64, DM / 64);
  gemm_xwT<true><<<gg, 256, 0, stream>>>(x, Wq, bq, Qb);
  gemm_xwT<true><<<gg, 256, 0, stream>>>(x, Wk, bk, Kb);
  gemm_xwT<true><<<gg, 256, 0, stream>>>(x, Wv, bv, Vb);

  topk_kernel<<<BHT, 1024, 0, stream>>>(Qb, tix);

  attn_kernel<<<dim3((TOPU + 15) / 16, BHT), 256, 0, stream>>>(Qb, Kb, Vb, tix, O1);

  gemm_xwT<false><<<gg, 256, 0, stream>>>(O1, Wo, bo, out);
}

// Round 2
// 623.476 us; speedup vs baseline: 3.2974x; 3.2974x over previous
//
#include <hip/hip_runtime.h>
#include <cstddef>
#include <cstdint>

constexpr int LSEQ = 4096;
constexpr int DM   = 1024;
constexpr int HD   = 64;
constexpr int BHT  = 32;     // B*H
constexpr int TOPU = 819;
constexpr int MROWS = 8192;  // B*L

typedef unsigned short u16;
typedef __attribute__((ext_vector_type(8))) short short8v;  // 8 bf16 (4 VGPR)
typedef __attribute__((ext_vector_type(4))) short short4v;  // 4 bf16 (8B)
typedef __attribute__((ext_vector_type(4))) float f32x4;

__device__ __forceinline__ u16 f2bf(float f) {
  uint32_t u = __float_as_uint(f);
  u += 0x7fffu + ((u >> 16) & 1u);   // RNE
  return (u16)(u >> 16);
}

// ---------------------------------------------------------------------------
// fp32 GEMM (Q projection only -- precision-critical for top-k selection).
// Y = X @ W^T + bias, written to split-head layout [(b*16+h), l, d].
// ---------------------------------------------------------------------------
__global__ __launch_bounds__(256) void gemm_xwT_f32(
    const float* __restrict__ X, const float* __restrict__ W,
    const float* __restrict__ bias, float* __restrict__ Y)
{
  __shared__ float As[16][68];
  __shared__ float Bs[16][68];
  const int tid = threadIdx.x;
  const int tx = tid & 15, ty = tid >> 4;
  const int m0 = blockIdx.x * 64, n0 = blockIdx.y * 64;

  const int lr = tid >> 2;
  const int lc = (tid & 3) * 4;
  const float* Xp = X + (size_t)(m0 + lr) * DM + lc;
  const float* Wp = W + (size_t)(n0 + lr) * DM + lc;

  float acc[4][4] = {};

  for (int k0 = 0; k0 < DM; k0 += 16) {
    float4 xv = *reinterpret_cast<const float4*>(Xp + k0);
    float4 wv = *reinterpret_cast<const float4*>(Wp + k0);
    As[lc+0][lr] = xv.x; As[lc+1][lr] = xv.y; As[lc+2][lr] = xv.z; As[lc+3][lr] = xv.w;
    Bs[lc+0][lr] = wv.x; Bs[lc+1][lr] = wv.y; Bs[lc+2][lr] = wv.z; Bs[lc+3][lr] = wv.w;
    __syncthreads();
    #pragma unroll
    for (int kk = 0; kk < 16; ++kk) {
      float a[4], b[4];
      *reinterpret_cast<float4*>(a) = *reinterpret_cast<const float4*>(&As[kk][ty * 4]);
      *reinterpret_cast<float4*>(b) = *reinterpret_cast<const float4*>(&Bs[kk][tx * 4]);
      #pragma unroll
      for (int i = 0; i < 4; ++i)
        #pragma unroll
        for (int j = 0; j < 4; ++j)
          acc[i][j] = fmaf(a[i], b[j], acc[i][j]);
    }
    __syncthreads();
  }

  float bb[4];
  *reinterpret_cast<float4*>(bb) = *reinterpret_cast<const float4*>(bias + n0 + tx * 4);

  #pragma unroll
  for (int i = 0; i < 4; ++i) {
    const int m = m0 + ty * 4 + i;
    float4 o;
    o.x = acc[i][0] + bb[0];
    o.y = acc[i][1] + bb[1];
    o.z = acc[i][2] + bb[2];
    o.w = acc[i][3] + bb[3];
    const int b = m >> 12, l = m & (LSEQ - 1);
    float* dst = Y + ((size_t)((b << 4) + blockIdx.y) * LSEQ + l) * HD + tx * 4;
    *reinterpret_cast<float4*>(dst) = o;
  }
}

// ---------------------------------------------------------------------------
// fp32 -> bf16 bulk convert (8 elems / thread)
// ---------------------------------------------------------------------------
__global__ __launch_bounds__(256) void conv_bf16(
    const float* __restrict__ src, u16* __restrict__ dst, int n8)
{
  int i = blockIdx.x * 256 + threadIdx.x;
  if (i >= n8) return;
  const float4 a = *reinterpret_cast<const float4*>(src + (size_t)i * 8);
  const float4 b = *reinterpret_cast<const float4*>(src + (size_t)i * 8 + 4);
  short8v v;
  v[0] = (short)f2bf(a.x); v[1] = (short)f2bf(a.y);
  v[2] = (short)f2bf(a.z); v[3] = (short)f2bf(a.w);
  v[4] = (short)f2bf(b.x); v[5] = (short)f2bf(b.y);
  v[6] = (short)f2bf(b.z); v[7] = (short)f2bf(b.w);
  *reinterpret_cast<short8v*>(dst + (size_t)i * 8) = v;
}

// ---------------------------------------------------------------------------
// bf16 MFMA GEMM: Y = Xb @ Wb^T + bias.  128x128 tile, BK=32, 4 waves (2x2),
// each wave 64x64 out (16 mfma_f32_16x16x32_bf16 per K-step).
// LDS tiles [128][32] bf16 with XOR swizzle (elem ^= (row&7)<<3) so that all
// fragment ds_read_b128s are bank-uniform.
// MODE 0: bf16 out, split-head layout (K/V projections)
// MODE 1: fp32 out, row-major [M][1024] (final output GEMM)
// ---------------------------------------------------------------------------
template<int MODE>
__global__ __launch_bounds__(256) void gemm_bf16(
    const u16* __restrict__ Xb, const u16* __restrict__ Wb,
    const float* __restrict__ bias, void* __restrict__ Yout)
{
  __shared__ u16 As[128 * 32];
  __shared__ u16 Bs[128 * 32];
  const int tid = threadIdx.x;
  const int m0 = blockIdx.x * 128, n0 = blockIdx.y * 128;
  const int wid = tid >> 6, lane = tid & 63;
  const int wr = (wid >> 1) * 64, wc = (wid & 1) * 64;
  const int c = lane & 15, G = lane >> 4;

  f32x4 acc[4][4];
  #pragma unroll
  for (int mt = 0; mt < 4; ++mt)
    #pragma unroll
    for (int nt = 0; nt < 4; ++nt)
      acc[mt][nt] = (f32x4){0.f, 0.f, 0.f, 0.f};

  for (int k0 = 0; k0 < DM; k0 += 32) {
    #pragma unroll
    for (int rr = 0; rr < 2; ++rr) {
      const int id = tid + rr * 256;
      const int row = id >> 2, kc = id & 3;
      short8v a = *reinterpret_cast<const short8v*>(Xb + (size_t)(m0 + row) * DM + k0 + kc * 8);
      short8v b = *reinterpret_cast<const short8v*>(Wb + (size_t)(n0 + row) * DM + k0 + kc * 8);
      const int e = (row * 32 + kc * 8) ^ ((row & 7) << 3);
      *reinterpret_cast<short8v*>(As + e) = a;
      *reinterpret_cast<short8v*>(Bs + e) = b;
    }
    __syncthreads();

    short8v af[4], bf[4];
    #pragma unroll
    for (int mt = 0; mt < 4; ++mt) {
      const int m = wr + mt * 16 + c;
      af[mt] = *reinterpret_cast<const short8v*>(As + ((m * 32 + G * 8) ^ ((m & 7) << 3)));
      const int n = wc + mt * 16 + c;
      bf[mt] = *reinterpret_cast<const short8v*>(Bs + ((n * 32 + G * 8) ^ ((n & 7) << 3)));
    }
    #pragma unroll
    for (int mt = 0; mt < 4; ++mt)
      #pragma unroll
      for (int nt = 0; nt < 4; ++nt)
        acc[mt][nt] = __builtin_amdgcn_mfma_f32_16x16x32_bf16(af[mt], bf[nt], acc[mt][nt], 0, 0, 0);
    __syncthreads();
  }

  float bb[4];
  #pragma unroll
  for (int nt = 0; nt < 4; ++nt) bb[nt] = bias[n0 + wc + nt * 16 + c];

  #pragma unroll
  for (int mt = 0; mt < 4; ++mt) {
    #pragma unroll
    for (int nt = 0; nt < 4; ++nt) {
      const int n = n0 + wc + nt * 16 + c;
      #pragma unroll
      for (int r = 0; r < 4; ++r) {
        const int m = m0 + wr + mt * 16 + G * 4 + r;
        const float val = acc[mt][nt][r] + bb[nt];
        if (MODE == 0) {
          const int b = m >> 12, l = m & (LSEQ - 1), h = n >> 6, d = n & 63;
          u16* Y = (u16*)Yout;
          Y[((size_t)((b << 4) + h) * LSEQ + l) * HD + d] = f2bf(val);
        } else {
          float* Y = (float*)Yout;
          Y[(size_t)m * DM + n] = val;
        }
      }
    }
  }
}

// ---------------------------------------------------------------------------
// top-k by Q-row L2 norm (fp32 Q) -- bitonic sort of packed (bits<<32)|~idx.
// ---------------------------------------------------------------------------
__global__ __launch_bounds__(1024) void topk_kernel(
    const float* __restrict__ Q, int* __restrict__ top_idx)
{
  __shared__ unsigned long long keys[LSEQ];
  const int bh = blockIdx.x;
  const float* Qb = Q + (size_t)bh * LSEQ * HD;

  for (int l = threadIdx.x; l < LSEQ; l += 1024) {
    const float4* row = reinterpret_cast<const float4*>(Qb + (size_t)l * HD);
    float s = 0.f;
    #pragma unroll
    for (int i = 0; i < 16; ++i) {
      float4 v = row[i];
      s += v.x * v.x + v.y * v.y + v.z * v.z + v.w * v.w;
    }
    keys[l] = ((unsigned long long)__float_as_uint(s) << 32) |
              (unsigned long long)(unsigned int)(~l);
  }
  __syncthreads();

  for (int k = 2; k <= LSEQ; k <<= 1) {
    for (int j = k >> 1; j > 0; j >>= 1) {
      for (int t = threadIdx.x; t < LSEQ; t += 1024) {
        const int ixj = t ^ j;
        if (ixj > t) {
          const bool desc = ((t & k) == 0);
          unsigned long long a = keys[t], b = keys[ixj];
          if (desc ? (a < b) : (a > b)) { keys[t] = b; keys[ixj] = a; }
        }
      }
      __syncthreads();
    }
  }

  for (int r = threadIdx.x; r < TOPU; r += 1024)
    top_idx[bh * TOPU + r] = (int)(~(unsigned int)(keys[r] & 0xffffffffu));
}

// ---------------------------------------------------------------------------
// MFMA flash attention over selected rows.
// Block: 4 waves x 16 q-rows = 64 rows. Chunk = 64 keys.
// QK^T: A=Q (regs, fp32 Q * 0.125 -> bf16), B=K (swizzled LDS). D: q=(G*4+r), key=c.
// softmax: shfl_xor over the 16-lane key groups, online m/lsum per q-row.
// PV as O^T = V^T @ P: A=V^T from Vt[d][key] (two-stage LDS transpose),
//   B=P from per-wave Pt[q][key]. D: d=(G*4+r) within tile, q=c.
// Output scattered to O1b bf16 [B*L][1024] (pre-zeroed).
// ---------------------------------------------------------------------------
__global__ __launch_bounds__(256) void attn_mfma(
    const float* __restrict__ Qf, const u16* __restrict__ Kg,
    const u16* __restrict__ Vg, const int* __restrict__ tix,
    u16* __restrict__ O1b)
{
  __shared__ u16 Kc[64 * 64];      // [key][d], elem ^= (key&7)<<3
  __shared__ u16 Vc[64 * 64];      // same layout (staging for transpose)
  __shared__ u16 Vt[64 * 72];      // [d][key], stride 72
  __shared__ u16 Pt[4][16 * 72];   // per-wave [q][key], stride 72

  const int tid = threadIdx.x;
  const int wid = tid >> 6, lane = tid & 63;
  const int c = lane & 15, G = lane >> 4;
  const int bh = blockIdx.y;
  const size_t bhL = (size_t)bh * LSEQ;

  const int rglob = blockIdx.x * 64 + wid * 16 + c;
  const int rowidx = (rglob < TOPU) ? tix[bh * TOPU + rglob] : -1;

  // Q fragments: lane holds Q[q=c][d = G*8 + j (+32*kf)] * scale
  short8v qf[2];
  #pragma unroll
  for (int kf = 0; kf < 2; ++kf) {
    if (rowidx >= 0) {
      const float* qp = Qf + (bhL + rowidx) * HD + kf * 32 + G * 8;
      const float4 x0 = *reinterpret_cast<const float4*>(qp);
      const float4 x1 = *reinterpret_cast<const float4*>(qp + 4);
      short8v v;
      v[0] = (short)f2bf(x0.x * 0.125f); v[1] = (short)f2bf(x0.y * 0.125f);
      v[2] = (short)f2bf(x0.z * 0.125f); v[3] = (short)f2bf(x0.w * 0.125f);
      v[4] = (short)f2bf(x1.x * 0.125f); v[5] = (short)f2bf(x1.y * 0.125f);
      v[6] = (short)f2bf(x1.z * 0.125f); v[7] = (short)f2bf(x1.w * 0.125f);
      qf[kf] = v;
    } else {
      short8v v;
      #pragma unroll
      for (int j = 0; j < 8; ++j) v[j] = 0;
      qf[kf] = v;
    }
  }

  float mrow[4], lsum[4];
  #pragma unroll
  for (int r = 0; r < 4; ++r) { mrow[r] = -1e30f; lsum[r] = 0.f; }
  f32x4 oacc[4];
  #pragma unroll
  for (int dt = 0; dt < 4; ++dt) oacc[dt] = (f32x4){0.f, 0.f, 0.f, 0.f};

  for (int t64 = 0; t64 < LSEQ / 64; ++t64) {
    // ---- stage K,V chunk into swizzled LDS (coalesced 16B loads) ----
    #pragma unroll
    for (int rr = 0; rr < 2; ++rr) {
      const int id = tid + rr * 256;
      const int key = id >> 3, dg = id & 7;
      const size_t go = (bhL + t64 * 64 + key) * HD + dg * 8;
      short8v kv = *reinterpret_cast<const short8v*>(Kg + go);
      short8v vv = *reinterpret_cast<const short8v*>(Vg + go);
      const int e = (key * 64 + dg * 8) ^ ((key & 7) << 3);
      *reinterpret_cast<short8v*>(Kc + e) = kv;
      *reinterpret_cast<short8v*>(Vc + e) = vv;
    }
    __syncthreads();

    // ---- transpose Vc -> Vt (conflict-free column reads) ----
    #pragma unroll
    for (int rr = 0; rr < 2; ++rr) {
      const int unit = tid + rr * 256;
      const int d = unit & 63, kc8 = (unit >> 6) & 7;
      short8v v;
      #pragma unroll
      for (int i = 0; i < 8; ++i) {
        const int key = kc8 * 8 + i;
        v[i] = (short)Vc[(key * 64 + d) ^ (i << 3)];
      }
      *reinterpret_cast<short8v*>(Vt + d * 72 + kc8 * 8) = v;
    }

    // ---- QK^T MFMAs: sacc[kt], q=(G*4+r), key=kt*16+c ----
    f32x4 sacc[4];
    #pragma unroll
    for (int kt = 0; kt < 4; ++kt) {
      sacc[kt] = (f32x4){0.f, 0.f, 0.f, 0.f};
      const int key = kt * 16 + c;
      #pragma unroll
      for (int kf = 0; kf < 2; ++kf) {
        short8v kb = *reinterpret_cast<const short8v*>(
            Kc + ((key * 64 + kf * 32 + G * 8) ^ ((key & 7) << 3)));
        sacc[kt] = __builtin_amdgcn_mfma_f32_16x16x32_bf16(qf[kf], kb, sacc[kt], 0, 0, 0);
      }
    }

    // ---- online softmax (per q-row = (G,r); key reduction via shfl 1,2,4,8) ----
    float p[4][4];   // [kt][r]
    float corrs[4];
    #pragma unroll
    for (int r = 0; r < 4; ++r) {
      float v = fmaxf(fmaxf(sacc[0][r], sacc[1][r]), fmaxf(sacc[2][r], sacc[3][r]));
      v = fmaxf(v, __shfl_xor(v, 1));
      v = fmaxf(v, __shfl_xor(v, 2));
      v = fmaxf(v, __shfl_xor(v, 4));
      v = fmaxf(v, __shfl_xor(v, 8));
      const float mnew = fmaxf(mrow[r], v);
      corrs[r] = __expf(mrow[r] - mnew);
      float ps = 0.f;
      #pragma unroll
      for (int kt = 0; kt < 4; ++kt) { p[kt][r] = __expf(sacc[kt][r] - mnew); ps += p[kt][r]; }
      ps += __shfl_xor(ps, 1);
      ps += __shfl_xor(ps, 2);
      ps += __shfl_xor(ps, 4);
      ps += __shfl_xor(ps, 8);
      lsum[r] = lsum[r] * corrs[r] + ps;
      mrow[r] = mnew;
    }

    // gather corr for q = c (PV layout) and rescale O accumulator
    float cq[4];
    #pragma unroll
    for (int r = 0; r < 4; ++r) cq[r] = __shfl(corrs[r], (c >> 2) << 4);
    {
      const float lo = (c & 1) ? cq[1] : cq[0];
      const float hi = (c & 1) ? cq[3] : cq[2];
      const float corr_q = (c & 2) ? hi : lo;
      #pragma unroll
      for (int dt = 0; dt < 4; ++dt) oacc[dt] *= corr_q;
    }

    // ---- P -> bf16 into per-wave Pt[q][key] ----
    #pragma unroll
    for (int kt = 0; kt < 4; ++kt)
      #pragma unroll
      for (int r = 0; r < 4; ++r)
        Pt[wid][(G * 4 + r) * 72 + kt * 16 + c] = f2bf(p[kt][r]);

    __syncthreads();

    // ---- PV: O^T += V^T @ P  (A = Vt rows, B = Pt rows) ----
    #pragma unroll
    for (int kf = 0; kf < 2; ++kf) {
      short8v pf = *reinterpret_cast<const short8v*>(&Pt[wid][c * 72 + kf * 32 + G * 8]);
      #pragma unroll
      for (int dt = 0; dt < 4; ++dt) {
        short8v vf = *reinterpret_cast<const short8v*>(Vt + (dt * 16 + c) * 72 + kf * 32 + G * 8);
        oacc[dt] = __builtin_amdgcn_mfma_f32_16x16x32_bf16(vf, pf, oacc[dt], 0, 0, 0);
      }
    }
    __syncthreads();
  }

  // ---- epilogue: gather 1/lsum for q=c, write O^T frags (4 consecutive d, 8B) ----
  float lq[4];
  #pragma unroll
  for (int r = 0; r < 4; ++r) lq[r] = __shfl(lsum[r], (c >> 2) << 4);
  const float lo = (c & 1) ? lq[1] : lq[0];
  const float hi = (c & 1) ? lq[3] : lq[2];
  const float linv = 1.0f / ((c & 2) ? hi : lo);

  if (rowidx >= 0) {
    const int b = bh >> 4, h = bh & 15;
    u16* base = O1b + (size_t)(b * LSEQ + rowidx) * DM + h * HD;
    #pragma unroll
    for (int dt = 0; dt < 4; ++dt) {
      short4v o;
      o[0] = (short)f2bf(oacc[dt][0] * linv);
      o[1] = (short)f2bf(oacc[dt][1] * linv);
      o[2] = (short)f2bf(oacc[dt][2] * linv);
      o[3] = (short)f2bf(oacc[dt][3] * linv);
      *reinterpret_cast<short4v*>(base + dt * 16 + G * 4) = o;
    }
  }
}

// ---------------------------------------------------------------------------
extern "C" void kernel_launch(void* const* d_in, const int* in_sizes, int n_in,
                              void* d_out, int out_size, void* d_ws, size_t ws_size,
                              hipStream_t stream) {
  const float* x  = (const float*)d_in[0];
  const float* Wq = (const float*)d_in[1];
  const float* bq = (const float*)d_in[2];
  const float* Wk = (const float*)d_in[3];
  const float* bk = (const float*)d_in[4];
  const float* Wv = (const float*)d_in[5];
  const float* bv = (const float*)d_in[6];
  const float* Wo = (const float*)d_in[7];
  const float* bo = (const float*)d_in[8];
  float* out = (float*)d_out;

  char* w = (char*)d_ws;
  float* Qb  = (float*)w;  w += (size_t)BHT * LSEQ * HD * 4;   // 32 MB fp32
  u16*   O1b = (u16*)w;    w += (size_t)MROWS * DM * 2;        // 16 MB bf16
  u16*   Kb  = (u16*)w;    w += (size_t)BHT * LSEQ * HD * 2;   // 16 MB bf16
  u16*   Vb  = (u16*)w;    w += (size_t)BHT * LSEQ * HD * 2;   // 16 MB bf16
  u16*   Xb  = (u16*)w;    w += (size_t)MROWS * DM * 2;        // 16 MB bf16
  u16*   Wkb = (u16*)w;    w += (size_t)DM * DM * 2;           // 2 MB
  u16*   Wvb = (u16*)w;    w += (size_t)DM * DM * 2;
  u16*   Wob = (u16*)w;    w += (size_t)DM * DM * 2;
  int*   tix = (int*)w;

  // bf16 conversions
  conv_bf16<<<4096, 256, 0, stream>>>(x,  Xb,  MROWS * DM / 8);
  conv_bf16<<<512,  256, 0, stream>>>(Wk, Wkb, DM * DM / 8);
  conv_bf16<<<512,  256, 0, stream>>>(Wv, Wvb, DM * DM / 8);
  conv_bf16<<<512,  256, 0, stream>>>(Wo, Wob, DM * DM / 8);

  // Q projection in fp32 (drives top-k selection)
  gemm_xwT_f32<<<dim3(MROWS / 64, DM / 64), 256, 0, stream>>>(x, Wq, bq, Qb);

  // K,V projections in bf16 MFMA (split-head bf16 output)
  gemm_bf16<0><<<dim3(MROWS / 128, DM / 128), 256, 0, stream>>>(Xb, Wkb, bk, (void*)Kb);
  gemm_bf16<0><<<dim3(MROWS / 128, DM / 128), 256, 0, stream>>>(Xb, Wvb, bv, (void*)Vb);

  topk_kernel<<<BHT, 1024, 0, stream>>>(Qb, tix);

  hipMemsetAsync(O1b, 0, (size_t)MROWS * DM * 2, stream);

  attn_mfma<<<dim3((TOPU + 63) / 64, BHT), 256, 0, stream>>>(Qb, Kb, Vb, tix, O1b);

  // final GEMM: out = O1b @ Wo^T + bo  (fp32 out)
  gemm_bf16<1><<<dim3(MROWS / 128, DM / 128), 256, 0, stream>>>(O1b, Wob, bo, (void*)out);
}

// Round 3
// 442.495 us; speedup vs baseline: 4.6460x; 1.4090x over previous
//
#include <hip/hip_runtime.h>
#include <cstddef>
#include <cstdint>

constexpr int LSEQ = 4096;
constexpr int DM   = 1024;
constexpr int HD   = 64;
constexpr int BHT  = 32;     // B*H
constexpr int TOPU = 819;
constexpr int MROWS = 8192;  // B*L

typedef unsigned short u16;
typedef __attribute__((ext_vector_type(8))) short short8v;  // 8 bf16 (4 VGPR)
typedef __attribute__((ext_vector_type(4))) short short4v;  // 4 bf16 (8B)
typedef __attribute__((ext_vector_type(4))) float f32x4;

__device__ __forceinline__ u16 f2bf(float f) {
  uint32_t u = __float_as_uint(f);
  u += 0x7fffu + ((u >> 16) & 1u);   // RNE
  return (u16)(u >> 16);
}
__device__ __forceinline__ float bf2f(u16 h) {
  return __uint_as_float(((uint32_t)h) << 16);
}

// ---------------------------------------------------------------------------
// fp32 -> 3-piece bf16 split (x ~= p1+p2+p3 to ~2^-24 rel).  8 elems/thread.
// ---------------------------------------------------------------------------
__global__ __launch_bounds__(256) void split3_kernel(
    const float* __restrict__ src, u16* __restrict__ p1,
    u16* __restrict__ p2, u16* __restrict__ p3, int n8)
{
  int i = blockIdx.x * 256 + threadIdx.x;
  if (i >= n8) return;
  const float4 a = *reinterpret_cast<const float4*>(src + (size_t)i * 8);
  const float4 b = *reinterpret_cast<const float4*>(src + (size_t)i * 8 + 4);
  float e[8] = {a.x, a.y, a.z, a.w, b.x, b.y, b.z, b.w};
  short8v v1, v2, v3;
  #pragma unroll
  for (int j = 0; j < 8; ++j) {
    u16 h1 = f2bf(e[j]);        float r1 = e[j] - bf2f(h1);
    u16 h2 = f2bf(r1);          float r2 = r1 - bf2f(h2);
    u16 h3 = f2bf(r2);
    v1[j] = (short)h1; v2[j] = (short)h2; v3[j] = (short)h3;
  }
  *reinterpret_cast<short8v*>(p1 + (size_t)i * 8) = v1;
  *reinterpret_cast<short8v*>(p2 + (size_t)i * 8) = v2;
  *reinterpret_cast<short8v*>(p3 + (size_t)i * 8) = v3;
}

// ---------------------------------------------------------------------------
// fp32 -> bf16 bulk convert (8 elems / thread)
// ---------------------------------------------------------------------------
__global__ __launch_bounds__(256) void conv_bf16(
    const float* __restrict__ src, u16* __restrict__ dst, int n8)
{
  int i = blockIdx.x * 256 + threadIdx.x;
  if (i >= n8) return;
  const float4 a = *reinterpret_cast<const float4*>(src + (size_t)i * 8);
  const float4 b = *reinterpret_cast<const float4*>(src + (size_t)i * 8 + 4);
  short8v v;
  v[0] = (short)f2bf(a.x); v[1] = (short)f2bf(a.y);
  v[2] = (short)f2bf(a.z); v[3] = (short)f2bf(a.w);
  v[4] = (short)f2bf(b.x); v[5] = (short)f2bf(b.y);
  v[6] = (short)f2bf(b.z); v[7] = (short)f2bf(b.w);
  *reinterpret_cast<short8v*>(dst + (size_t)i * 8) = v;
}

// ---------------------------------------------------------------------------
// Q projection at fp32 accuracy via 3-piece split-bf16 MFMA:
// Q = X@W^T+b with X=X1+X2+X3, W=W1+W2+W3; products (1,1),(1,2),(2,1),(2,2),
// (1,3),(3,1) accumulated in fp32 (dropped terms ~2^-24 rel).
// 128x128 tile, BK=32, 4 waves; fp32 output in split-head layout.
// ---------------------------------------------------------------------------
__global__ __launch_bounds__(256) void gemm_q_split(
    const u16* __restrict__ X1, const u16* __restrict__ X2, const u16* __restrict__ X3,
    const u16* __restrict__ W1, const u16* __restrict__ W2, const u16* __restrict__ W3,
    const float* __restrict__ bias, float* __restrict__ Y)
{
  __shared__ u16 As[3][128 * 32];
  __shared__ u16 Bs[3][128 * 32];
  const int tid = threadIdx.x;
  const int m0 = blockIdx.x * 128, n0 = blockIdx.y * 128;
  const int wid = tid >> 6, lane = tid & 63;
  const int wr = (wid >> 1) * 64, wc = (wid & 1) * 64;
  const int c = lane & 15, G = lane >> 4;

  f32x4 acc[4][4];
  #pragma unroll
  for (int mt = 0; mt < 4; ++mt)
    #pragma unroll
    for (int nt = 0; nt < 4; ++nt)
      acc[mt][nt] = (f32x4){0.f, 0.f, 0.f, 0.f};

  for (int k0 = 0; k0 < DM; k0 += 32) {
    #pragma unroll
    for (int rr = 0; rr < 2; ++rr) {
      const int id = tid + rr * 256;
      const int row = id >> 2, kc = id & 3;
      const size_t goA = (size_t)(m0 + row) * DM + k0 + kc * 8;
      const size_t goB = (size_t)(n0 + row) * DM + k0 + kc * 8;
      const int e = (row * 32 + kc * 8) ^ ((row & 7) << 3);
      *reinterpret_cast<short8v*>(As[0] + e) = *reinterpret_cast<const short8v*>(X1 + goA);
      *reinterpret_cast<short8v*>(As[1] + e) = *reinterpret_cast<const short8v*>(X2 + goA);
      *reinterpret_cast<short8v*>(As[2] + e) = *reinterpret_cast<const short8v*>(X3 + goA);
      *reinterpret_cast<short8v*>(Bs[0] + e) = *reinterpret_cast<const short8v*>(W1 + goB);
      *reinterpret_cast<short8v*>(Bs[1] + e) = *reinterpret_cast<const short8v*>(W2 + goB);
      *reinterpret_cast<short8v*>(Bs[2] + e) = *reinterpret_cast<const short8v*>(W3 + goB);
    }
    __syncthreads();

    short8v bf[3][4];
    #pragma unroll
    for (int nt = 0; nt < 4; ++nt) {
      const int n = wc + nt * 16 + c;
      const int eo = (n * 32 + G * 8) ^ ((n & 7) << 3);
      bf[0][nt] = *reinterpret_cast<const short8v*>(Bs[0] + eo);
      bf[1][nt] = *reinterpret_cast<const short8v*>(Bs[1] + eo);
      bf[2][nt] = *reinterpret_cast<const short8v*>(Bs[2] + eo);
    }
    #pragma unroll
    for (int mt = 0; mt < 4; ++mt) {
      const int m = wr + mt * 16 + c;
      const int eo = (m * 32 + G * 8) ^ ((m & 7) << 3);
      short8v a1 = *reinterpret_cast<const short8v*>(As[0] + eo);
      short8v a2 = *reinterpret_cast<const short8v*>(As[1] + eo);
      short8v a3 = *reinterpret_cast<const short8v*>(As[2] + eo);
      #pragma unroll
      for (int nt = 0; nt < 4; ++nt) {
        acc[mt][nt] = __builtin_amdgcn_mfma_f32_16x16x32_bf16(a1, bf[0][nt], acc[mt][nt], 0, 0, 0);
        acc[mt][nt] = __builtin_amdgcn_mfma_f32_16x16x32_bf16(a1, bf[1][nt], acc[mt][nt], 0, 0, 0);
        acc[mt][nt] = __builtin_amdgcn_mfma_f32_16x16x32_bf16(a2, bf[0][nt], acc[mt][nt], 0, 0, 0);
        acc[mt][nt] = __builtin_amdgcn_mfma_f32_16x16x32_bf16(a2, bf[1][nt], acc[mt][nt], 0, 0, 0);
        acc[mt][nt] = __builtin_amdgcn_mfma_f32_16x16x32_bf16(a1, bf[2][nt], acc[mt][nt], 0, 0, 0);
        acc[mt][nt] = __builtin_amdgcn_mfma_f32_16x16x32_bf16(a3, bf[0][nt], acc[mt][nt], 0, 0, 0);
      }
    }
    __syncthreads();
  }

  float bb[4];
  #pragma unroll
  for (int nt = 0; nt < 4; ++nt) bb[nt] = bias[n0 + wc + nt * 16 + c];

  #pragma unroll
  for (int mt = 0; mt < 4; ++mt) {
    #pragma unroll
    for (int nt = 0; nt < 4; ++nt) {
      const int n = n0 + wc + nt * 16 + c;
      const int h = n >> 6, d = n & 63;
      #pragma unroll
      for (int r = 0; r < 4; ++r) {
        const int m = m0 + wr + mt * 16 + G * 4 + r;
        const int b = m >> 12, l = m & (LSEQ - 1);
        Y[((size_t)((b << 4) + h) * LSEQ + l) * HD + d] = acc[mt][nt][r] + bb[nt];
      }
    }
  }
}

// ---------------------------------------------------------------------------
// bf16 MFMA GEMM: Y = Xb @ Wb^T + bias.  128x128 tile, BK=32, 4 waves.
// MODE 0: bf16 out, split-head layout.  MODE 1: fp32 out, row-major.
// ---------------------------------------------------------------------------
template<int MODE>
__global__ __launch_bounds__(256) void gemm_bf16(
    const u16* __restrict__ Xb, const u16* __restrict__ Wb,
    const float* __restrict__ bias, void* __restrict__ Yout)
{
  __shared__ u16 As[128 * 32];
  __shared__ u16 Bs[128 * 32];
  const int tid = threadIdx.x;
  const int m0 = blockIdx.x * 128, n0 = blockIdx.y * 128;
  const int wid = tid >> 6, lane = tid & 63;
  const int wr = (wid >> 1) * 64, wc = (wid & 1) * 64;
  const int c = lane & 15, G = lane >> 4;

  f32x4 acc[4][4];
  #pragma unroll
  for (int mt = 0; mt < 4; ++mt)
    #pragma unroll
    for (int nt = 0; nt < 4; ++nt)
      acc[mt][nt] = (f32x4){0.f, 0.f, 0.f, 0.f};

  for (int k0 = 0; k0 < DM; k0 += 32) {
    #pragma unroll
    for (int rr = 0; rr < 2; ++rr) {
      const int id = tid + rr * 256;
      const int row = id >> 2, kc = id & 3;
      short8v a = *reinterpret_cast<const short8v*>(Xb + (size_t)(m0 + row) * DM + k0 + kc * 8);
      short8v b = *reinterpret_cast<const short8v*>(Wb + (size_t)(n0 + row) * DM + k0 + kc * 8);
      const int e = (row * 32 + kc * 8) ^ ((row & 7) << 3);
      *reinterpret_cast<short8v*>(As + e) = a;
      *reinterpret_cast<short8v*>(Bs + e) = b;
    }
    __syncthreads();

    short8v af[4], bf[4];
    #pragma unroll
    for (int mt = 0; mt < 4; ++mt) {
      const int m = wr + mt * 16 + c;
      af[mt] = *reinterpret_cast<const short8v*>(As + ((m * 32 + G * 8) ^ ((m & 7) << 3)));
      const int n = wc + mt * 16 + c;
      bf[mt] = *reinterpret_cast<const short8v*>(Bs + ((n * 32 + G * 8) ^ ((n & 7) << 3)));
    }
    #pragma unroll
    for (int mt = 0; mt < 4; ++mt)
      #pragma unroll
      for (int nt = 0; nt < 4; ++nt)
        acc[mt][nt] = __builtin_amdgcn_mfma_f32_16x16x32_bf16(af[mt], bf[nt], acc[mt][nt], 0, 0, 0);
    __syncthreads();
  }

  float bb[4];
  #pragma unroll
  for (int nt = 0; nt < 4; ++nt) bb[nt] = bias[n0 + wc + nt * 16 + c];

  #pragma unroll
  for (int mt = 0; mt < 4; ++mt) {
    #pragma unroll
    for (int nt = 0; nt < 4; ++nt) {
      const int n = n0 + wc + nt * 16 + c;
      #pragma unroll
      for (int r = 0; r < 4; ++r) {
        const int m = m0 + wr + mt * 16 + G * 4 + r;
        const float val = acc[mt][nt][r] + bb[nt];
        if (MODE == 0) {
          const int b = m >> 12, l = m & (LSEQ - 1), h = n >> 6, d = n & 63;
          u16* Y = (u16*)Yout;
          Y[((size_t)((b << 4) + h) * LSEQ + l) * HD + d] = f2bf(val);
        } else {
          float* Y = (float*)Yout;
          Y[(size_t)m * DM + n] = val;
        }
      }
    }
  }
}

// ---------------------------------------------------------------------------
// Per-row squared L2 norms of Q (fp32).  One row (64 floats) per thread.
// ---------------------------------------------------------------------------
__global__ __launch_bounds__(256) void norms_kernel(
    const float* __restrict__ Q, float* __restrict__ norms)
{
  const int r = blockIdx.x * 256 + threadIdx.x;   // 0 .. BHT*LSEQ-1
  const float4* row = reinterpret_cast<const float4*>(Q + (size_t)r * HD);
  float s = 0.f;
  #pragma unroll
  for (int i = 0; i < 16; ++i) {
    float4 v = row[i];
    s += v.x * v.x + v.y * v.y + v.z * v.z + v.w * v.w;
  }
  norms[r] = s;
}

// ---------------------------------------------------------------------------
// Per-bh top-TOPU selection (set only -- scatter makes order irrelevant).
// Byte-radix select of the TOPU-th largest key (fp32 bits, all >= 0), then
// deterministic stable compaction: all keys > T, then first (ascending index)
// keys == T -- exact jax.lax.top_k tie semantics, set-wise.
// ---------------------------------------------------------------------------
__global__ __launch_bounds__(1024) void select_topk(
    const float* __restrict__ norms, int* __restrict__ top_idx)
{
  __shared__ unsigned int keys[LSEQ];       // 16 KB
  __shared__ unsigned int hist[256];
  __shared__ unsigned int wsums[16];
  __shared__ unsigned int sh_b, sh_above;

  const int tid = threadIdx.x;
  const int bh = blockIdx.x;

  for (int l = tid; l < LSEQ; l += 1024)
    keys[l] = __float_as_uint(norms[bh * LSEQ + l]);
  __syncthreads();

  unsigned int prefix = 0, rem = TOPU, total_gt = 0;
  for (int shift = 24; shift >= 0; shift -= 8) {
    if (tid < 256) hist[tid] = 0;
    __syncthreads();
    for (int l = tid; l < LSEQ; l += 1024) {
      const unsigned int k = keys[l];
      const bool in = (shift == 24) || ((k >> (shift + 8)) == prefix);
      if (in) atomicAdd(&hist[(k >> shift) & 255], 1);
    }
    __syncthreads();
    if (tid == 0) {
      unsigned int cum = 0; int b = 255;
      for (; b > 0; --b) {
        const unsigned int h = hist[b];
        if (cum + h >= rem) break;
        cum += h;
      }
      sh_b = (unsigned int)b; sh_above = cum;
    }
    __syncthreads();
    prefix = (prefix << 8) | sh_b;
    total_gt += sh_above;
    rem -= sh_above;
    __syncthreads();
  }
  const unsigned int T = prefix;   // rem >= 1 keys == T still needed

  const int lane = tid & 63, wv = tid >> 6;
  const int l0 = tid * 4;

  // ---- pass 1: keys > T (stable, ascending index) ----
  {
    unsigned int flags = 0; int cnt = 0;
    #pragma unroll
    for (int j = 0; j < 4; ++j)
      if (keys[l0 + j] > T) { flags |= 1u << j; ++cnt; }
    int incl = cnt;
    #pragma unroll
    for (int off = 1; off < 64; off <<= 1) {
      int nv = __shfl_up(incl, off);
      if (lane >= off) incl += nv;
    }
    if (lane == 63) wsums[wv] = (unsigned int)incl;
    __syncthreads();
    if (tid == 0) {
      unsigned int run = 0;
      for (int w = 0; w < 16; ++w) { unsigned int t = wsums[w]; wsums[w] = run; run += t; }
    }
    __syncthreads();
    unsigned int pos = wsums[wv] + (unsigned int)(incl - cnt);
    #pragma unroll
    for (int j = 0; j < 4; ++j)
      if (flags & (1u << j)) top_idx[bh * TOPU + (pos++)] = l0 + j;
  }
  __syncthreads();

  // ---- pass 2: first `rem` keys == T, ascending index ----
  {
    unsigned int flags = 0; int cnt = 0;
    #pragma unroll
    for (int j = 0; j < 4; ++j)
      if (keys[l0 + j] == T) { flags |= 1u << j; ++cnt; }
    int incl = cnt;
    #pragma unroll
    for (int off = 1; off < 64; off <<= 1) {
      int nv = __shfl_up(incl, off);
      if (lane >= off) incl += nv;
    }
    if (lane == 63) wsums[wv] = (unsigned int)incl;
    __syncthreads();
    if (tid == 0) {
      unsigned int run = 0;
      for (int w = 0; w < 16; ++w) { unsigned int t = wsums[w]; wsums[w] = run; run += t; }
    }
    __syncthreads();
    unsigned int r0 = wsums[wv] + (unsigned int)(incl - cnt);
    #pragma unroll
    for (int j = 0; j < 4; ++j)
      if (flags & (1u << j)) {
        if (r0 < rem) top_idx[bh * TOPU + total_gt + r0] = l0 + j;
        ++r0;
      }
  }
}

// ---------------------------------------------------------------------------
// MFMA flash attention over selected rows (unchanged from round 2).
// ---------------------------------------------------------------------------
__global__ __launch_bounds__(256) void attn_mfma(
    const float* __restrict__ Qf, const u16* __restrict__ Kg,
    const u16* __restrict__ Vg, const int* __restrict__ tix,
    u16* __restrict__ O1b)
{
  __shared__ u16 Kc[64 * 64];
  __shared__ u16 Vc[64 * 64];
  __shared__ u16 Vt[64 * 72];
  __shared__ u16 Pt[4][16 * 72];

  const int tid = threadIdx.x;
  const int wid = tid >> 6, lane = tid & 63;
  const int c = lane & 15, G = lane >> 4;
  const int bh = blockIdx.y;
  const size_t bhL = (size_t)bh * LSEQ;

  const int rglob = blockIdx.x * 64 + wid * 16 + c;
  const int rowidx = (rglob < TOPU) ? tix[bh * TOPU + rglob] : -1;

  short8v qf[2];
  #pragma unroll
  for (int kf = 0; kf < 2; ++kf) {
    if (rowidx >= 0) {
      const float* qp = Qf + (bhL + rowidx) * HD + kf * 32 + G * 8;
      const float4 x0 = *reinterpret_cast<const float4*>(qp);
      const float4 x1 = *reinterpret_cast<const float4*>(qp + 4);
      short8v v;
      v[0] = (short)f2bf(x0.x * 0.125f); v[1] = (short)f2bf(x0.y * 0.125f);
      v[2] = (short)f2bf(x0.z * 0.125f); v[3] = (short)f2bf(x0.w * 0.125f);
      v[4] = (short)f2bf(x1.x * 0.125f); v[5] = (short)f2bf(x1.y * 0.125f);
      v[6] = (short)f2bf(x1.z * 0.125f); v[7] = (short)f2bf(x1.w * 0.125f);
      qf[kf] = v;
    } else {
      short8v v;
      #pragma unroll
      for (int j = 0; j < 8; ++j) v[j] = 0;
      qf[kf] = v;
    }
  }

  float mrow[4], lsum[4];
  #pragma unroll
  for (int r = 0; r < 4; ++r) { mrow[r] = -1e30f; lsum[r] = 0.f; }
  f32x4 oacc[4];
  #pragma unroll
  for (int dt = 0; dt < 4; ++dt) oacc[dt] = (f32x4){0.f, 0.f, 0.f, 0.f};

  for (int t64 = 0; t64 < LSEQ / 64; ++t64) {
    #pragma unroll
    for (int rr = 0; rr < 2; ++rr) {
      const int id = tid + rr * 256;
      const int key = id >> 3, dg = id & 7;
      const size_t go = (bhL + t64 * 64 + key) * HD + dg * 8;
      short8v kv = *reinterpret_cast<const short8v*>(Kg + go);
      short8v vv = *reinterpret_cast<const short8v*>(Vg + go);
      const int e = (key * 64 + dg * 8) ^ ((key & 7) << 3);
      *reinterpret_cast<short8v*>(Kc + e) = kv;
      *reinterpret_cast<short8v*>(Vc + e) = vv;
    }
    __syncthreads();

    #pragma unroll
    for (int rr = 0; rr < 2; ++rr) {
      const int unit = tid + rr * 256;
      const int d = unit & 63, kc8 = (unit >> 6) & 7;
      short8v v;
      #pragma unroll
      for (int i = 0; i < 8; ++i) {
        const int key = kc8 * 8 + i;
        v[i] = (short)Vc[(key * 64 + d) ^ (i << 3)];
      }
      *reinterpret_cast<short8v*>(Vt + d * 72 + kc8 * 8) = v;
    }

    f32x4 sacc[4];
    #pragma unroll
    for (int kt = 0; kt < 4; ++kt) {
      sacc[kt] = (f32x4){0.f, 0.f, 0.f, 0.f};
      const int key = kt * 16 + c;
      #pragma unroll
      for (int kf = 0; kf < 2; ++kf) {
        short8v kb = *reinterpret_cast<const short8v*>(
            Kc + ((key * 64 + kf * 32 + G * 8) ^ ((key & 7) << 3)));
        sacc[kt] = __builtin_amdgcn_mfma_f32_16x16x32_bf16(qf[kf], kb, sacc[kt], 0, 0, 0);
      }
    }

    float p[4][4];
    float corrs[4];
    #pragma unroll
    for (int r = 0; r < 4; ++r) {
      float v = fmaxf(fmaxf(sacc[0][r], sacc[1][r]), fmaxf(sacc[2][r], sacc[3][r]));
      v = fmaxf(v, __shfl_xor(v, 1));
      v = fmaxf(v, __shfl_xor(v, 2));
      v = fmaxf(v, __shfl_xor(v, 4));
      v = fmaxf(v, __shfl_xor(v, 8));
      const float mnew = fmaxf(mrow[r], v);
      corrs[r] = __expf(mrow[r] - mnew);
      float ps = 0.f;
      #pragma unroll
      for (int kt = 0; kt < 4; ++kt) { p[kt][r] = __expf(sacc[kt][r] - mnew); ps += p[kt][r]; }
      ps += __shfl_xor(ps, 1);
      ps += __shfl_xor(ps, 2);
      ps += __shfl_xor(ps, 4);
      ps += __shfl_xor(ps, 8);
      lsum[r] = lsum[r] * corrs[r] + ps;
      mrow[r] = mnew;
    }

    float cq[4];
    #pragma unroll
    for (int r = 0; r < 4; ++r) cq[r] = __shfl(corrs[r], (c >> 2) << 4);
    {
      const float lo = (c & 1) ? cq[1] : cq[0];
      const float hi = (c & 1) ? cq[3] : cq[2];
      const float corr_q = (c & 2) ? hi : lo;
      #pragma unroll
      for (int dt = 0; dt < 4; ++dt) oacc[dt] *= corr_q;
    }

    #pragma unroll
    for (int kt = 0; kt < 4; ++kt)
      #pragma unroll
      for (int r = 0; r < 4; ++r)
        Pt[wid][(G * 4 + r) * 72 + kt * 16 + c] = f2bf(p[kt][r]);

    __syncthreads();

    #pragma unroll
    for (int kf = 0; kf < 2; ++kf) {
      short8v pf = *reinterpret_cast<const short8v*>(&Pt[wid][c * 72 + kf * 32 + G * 8]);
      #pragma unroll
      for (int dt = 0; dt < 4; ++dt) {
        short8v vf = *reinterpret_cast<const short8v*>(Vt + (dt * 16 + c) * 72 + kf * 32 + G * 8);
        oacc[dt] = __builtin_amdgcn_mfma_f32_16x16x32_bf16(vf, pf, oacc[dt], 0, 0, 0);
      }
    }
    __syncthreads();
  }

  float lq[4];
  #pragma unroll
  for (int r = 0; r < 4; ++r) lq[r] = __shfl(lsum[r], (c >> 2) << 4);
  const float lo = (c & 1) ? lq[1] : lq[0];
  const float hi = (c & 1) ? lq[3] : lq[2];
  const float linv = 1.0f / ((c & 2) ? hi : lo);

  if (rowidx >= 0) {
    const int b = bh >> 4, h = bh & 15;
    u16* base = O1b + (size_t)(b * LSEQ + rowidx) * DM + h * HD;
    #pragma unroll
    for (int dt = 0; dt < 4; ++dt) {
      short4v o;
      o[0] = (short)f2bf(oacc[dt][0] * linv);
      o[1] = (short)f2bf(oacc[dt][1] * linv);
      o[2] = (short)f2bf(oacc[dt][2] * linv);
      o[3] = (short)f2bf(oacc[dt][3] * linv);
      *reinterpret_cast<short4v*>(base + dt * 16 + G * 4) = o;
    }
  }
}

// ---------------------------------------------------------------------------
extern "C" void kernel_launch(void* const* d_in, const int* in_sizes, int n_in,
                              void* d_out, int out_size, void* d_ws, size_t ws_size,
                              hipStream_t stream) {
  const float* x  = (const float*)d_in[0];
  const float* Wq = (const float*)d_in[1];
  const float* bq = (const float*)d_in[2];
  const float* Wk = (const float*)d_in[3];
  const float* bk = (const float*)d_in[4];
  const float* Wv = (const float*)d_in[5];
  const float* bv = (const float*)d_in[6];
  const float* Wo = (const float*)d_in[7];
  const float* bo = (const float*)d_in[8];
  float* out = (float*)d_out;

  // workspace layout (with sequential-reuse aliasing):
  char* w = (char*)d_ws;
  float* Qb = (float*)w;  w += (size_t)BHT * LSEQ * HD * 4;    // 32 MB fp32
  u16* x1   = (u16*)w;    w += (size_t)MROWS * DM * 2;         // 16 MB
  u16* x2   = (u16*)w;    w += (size_t)MROWS * DM * 2;         // 16 MB -> later O1b
  u16* x3   = (u16*)w;    w += (size_t)MROWS * DM * 2;         // 16 MB -> later Kb
  u16* Vb   = (u16*)w;    w += (size_t)BHT * LSEQ * HD * 2;    // 16 MB
  u16* Wkb  = (u16*)w;    w += (size_t)DM * DM * 2;            // 2 MB
  u16* Wvb  = (u16*)w;    w += (size_t)DM * DM * 2;
  u16* Wob  = (u16*)w;    w += (size_t)DM * DM * 2;
  u16* wq1  = (u16*)w;    w += (size_t)DM * DM * 2;            // -> later norms
  u16* wq2  = (u16*)w;    w += (size_t)DM * DM * 2;            // -> later tix
  u16* wq3  = (u16*)w;    w += (size_t)DM * DM * 2;

  u16*   O1b   = x2;               // reused after gemm_q_split
  u16*   Kb    = x3;               // reused after gemm_q_split
  float* norms = (float*)wq1;      // 512 KB, reused after gemm_q_split
  int*   tix   = (int*)wq2;        // 104 KB, reused after gemm_q_split

  // splits / conversions
  split3_kernel<<<4096, 256, 0, stream>>>(x,  x1,  x2,  x3,  MROWS * DM / 8);
  split3_kernel<<<512,  256, 0, stream>>>(Wq, wq1, wq2, wq3, DM * DM / 8);
  conv_bf16<<<512, 256, 0, stream>>>(Wk, Wkb, DM * DM / 8);
  conv_bf16<<<512, 256, 0, stream>>>(Wv, Wvb, DM * DM / 8);
  conv_bf16<<<512, 256, 0, stream>>>(Wo, Wob, DM * DM / 8);

  // Q projection at fp32 accuracy (6-product split-bf16 MFMA)
  gemm_q_split<<<dim3(MROWS / 128, DM / 128), 256, 0, stream>>>(
      x1, x2, x3, wq1, wq2, wq3, bq, Qb);

  // K,V projections (bf16), K overwrites x3, safe after Q gemm
  gemm_bf16<0><<<dim3(MROWS / 128, DM / 128), 256, 0, stream>>>(x1, Wkb, bk, (void*)Kb);
  gemm_bf16<0><<<dim3(MROWS / 128, DM / 128), 256, 0, stream>>>(x1, Wvb, bv, (void*)Vb);

  // selection
  norms_kernel<<<BHT * LSEQ / 256, 256, 0, stream>>>(Qb, norms);
  select_topk<<<BHT, 1024, 0, stream>>>(norms, tix);

  hipMemsetAsync(O1b, 0, (size_t)MROWS * DM * 2, stream);

  attn_mfma<<<dim3((TOPU + 63) / 64, BHT), 256, 0, stream>>>(Qb, Kb, Vb, tix, O1b);

  gemm_bf16<1><<<dim3(MROWS / 128, DM / 128), 256, 0, stream>>>(O1b, Wob, bo, (void*)out);
}

// Round 4
// 330.043 us; speedup vs baseline: 6.2290x; 1.3407x over previous
//
#include <hip/hip_runtime.h>
#include <cstddef>
#include <cstdint>

constexpr int LSEQ = 4096;
constexpr int DM   = 1024;
constexpr int HD   = 64;
constexpr int BHT  = 32;     // B*H
constexpr int TOPU = 819;
constexpr int MROWS = 8192;  // B*L

typedef unsigned short u16;
typedef __attribute__((ext_vector_type(8))) short short8v;  // 8 bf16 (4 VGPR)
typedef __attribute__((ext_vector_type(4))) short short4v;  // 4 bf16 (8B)
typedef __attribute__((ext_vector_type(4))) float f32x4;

__device__ __forceinline__ u16 f2bf(float f) {
  uint32_t u = __float_as_uint(f);
  u += 0x7fffu + ((u >> 16) & 1u);   // RNE
  return (u16)(u >> 16);
}
__device__ __forceinline__ float bf2f(u16 h) {
  return __uint_as_float(((uint32_t)h) << 16);
}

// ---------------------------------------------------------------------------
// fp32 -> 3-piece bf16 split (x ~= p1+p2+p3 to ~2^-24 rel).  8 elems/thread.
// ---------------------------------------------------------------------------
__global__ __launch_bounds__(256) void split3_kernel(
    const float* __restrict__ src, u16* __restrict__ p1,
    u16* __restrict__ p2, u16* __restrict__ p3, int n8)
{
  int i = blockIdx.x * 256 + threadIdx.x;
  if (i >= n8) return;
  const float4 a = *reinterpret_cast<const float4*>(src + (size_t)i * 8);
  const float4 b = *reinterpret_cast<const float4*>(src + (size_t)i * 8 + 4);
  float e[8] = {a.x, a.y, a.z, a.w, b.x, b.y, b.z, b.w};
  short8v v1, v2, v3;
  #pragma unroll
  for (int j = 0; j < 8; ++j) {
    u16 h1 = f2bf(e[j]);        float r1 = e[j] - bf2f(h1);
    u16 h2 = f2bf(r1);          float r2 = r1 - bf2f(h2);
    u16 h3 = f2bf(r2);
    v1[j] = (short)h1; v2[j] = (short)h2; v3[j] = (short)h3;
  }
  *reinterpret_cast<short8v*>(p1 + (size_t)i * 8) = v1;
  *reinterpret_cast<short8v*>(p2 + (size_t)i * 8) = v2;
  *reinterpret_cast<short8v*>(p3 + (size_t)i * 8) = v3;
}

// ---------------------------------------------------------------------------
// fp32 -> bf16 bulk convert (8 elems / thread)
// ---------------------------------------------------------------------------
__global__ __launch_bounds__(256) void conv_bf16(
    const float* __restrict__ src, u16* __restrict__ dst, int n8)
{
  int i = blockIdx.x * 256 + threadIdx.x;
  if (i >= n8) return;
  const float4 a = *reinterpret_cast<const float4*>(src + (size_t)i * 8);
  const float4 b = *reinterpret_cast<const float4*>(src + (size_t)i * 8 + 4);
  short8v v;
  v[0] = (short)f2bf(a.x); v[1] = (short)f2bf(a.y);
  v[2] = (short)f2bf(a.z); v[3] = (short)f2bf(a.w);
  v[4] = (short)f2bf(b.x); v[5] = (short)f2bf(b.y);
  v[6] = (short)f2bf(b.z); v[7] = (short)f2bf(b.w);
  *reinterpret_cast<short8v*>(dst + (size_t)i * 8) = v;
}

// ---------------------------------------------------------------------------
// Q projection at fp32 accuracy via 3-piece split-bf16 MFMA (6 products).
// 128x128 tile, BK=32, 4 waves; fp32 output in split-head layout.
// ---------------------------------------------------------------------------
__global__ __launch_bounds__(256) void gemm_q_split(
    const u16* __restrict__ X1, const u16* __restrict__ X2, const u16* __restrict__ X3,
    const u16* __restrict__ W1, const u16* __restrict__ W2, const u16* __restrict__ W3,
    const float* __restrict__ bias, float* __restrict__ Y)
{
  __shared__ u16 As[3][128 * 32];
  __shared__ u16 Bs[3][128 * 32];
  const int tid = threadIdx.x;
  const int m0 = blockIdx.x * 128, n0 = blockIdx.y * 128;
  const int wid = tid >> 6, lane = tid & 63;
  const int wr = (wid >> 1) * 64, wc = (wid & 1) * 64;
  const int c = lane & 15, G = lane >> 4;

  f32x4 acc[4][4];
  #pragma unroll
  for (int mt = 0; mt < 4; ++mt)
    #pragma unroll
    for (int nt = 0; nt < 4; ++nt)
      acc[mt][nt] = (f32x4){0.f, 0.f, 0.f, 0.f};

  for (int k0 = 0; k0 < DM; k0 += 32) {
    #pragma unroll
    for (int rr = 0; rr < 2; ++rr) {
      const int id = tid + rr * 256;
      const int row = id >> 2, kc = id & 3;
      const size_t goA = (size_t)(m0 + row) * DM + k0 + kc * 8;
      const size_t goB = (size_t)(n0 + row) * DM + k0 + kc * 8;
      const int e = (row * 32 + kc * 8) ^ ((row & 7) << 3);
      *reinterpret_cast<short8v*>(As[0] + e) = *reinterpret_cast<const short8v*>(X1 + goA);
      *reinterpret_cast<short8v*>(As[1] + e) = *reinterpret_cast<const short8v*>(X2 + goA);
      *reinterpret_cast<short8v*>(As[2] + e) = *reinterpret_cast<const short8v*>(X3 + goA);
      *reinterpret_cast<short8v*>(Bs[0] + e) = *reinterpret_cast<const short8v*>(W1 + goB);
      *reinterpret_cast<short8v*>(Bs[1] + e) = *reinterpret_cast<const short8v*>(W2 + goB);
      *reinterpret_cast<short8v*>(Bs[2] + e) = *reinterpret_cast<const short8v*>(W3 + goB);
    }
    __syncthreads();

    short8v bf[3][4];
    #pragma unroll
    for (int nt = 0; nt < 4; ++nt) {
      const int n = wc + nt * 16 + c;
      const int eo = (n * 32 + G * 8) ^ ((n & 7) << 3);
      bf[0][nt] = *reinterpret_cast<const short8v*>(Bs[0] + eo);
      bf[1][nt] = *reinterpret_cast<const short8v*>(Bs[1] + eo);
      bf[2][nt] = *reinterpret_cast<const short8v*>(Bs[2] + eo);
    }
    #pragma unroll
    for (int mt = 0; mt < 4; ++mt) {
      const int m = wr + mt * 16 + c;
      const int eo = (m * 32 + G * 8) ^ ((m & 7) << 3);
      short8v a1 = *reinterpret_cast<const short8v*>(As[0] + eo);
      short8v a2 = *reinterpret_cast<const short8v*>(As[1] + eo);
      short8v a3 = *reinterpret_cast<const short8v*>(As[2] + eo);
      #pragma unroll
      for (int nt = 0; nt < 4; ++nt) {
        acc[mt][nt] = __builtin_amdgcn_mfma_f32_16x16x32_bf16(a1, bf[0][nt], acc[mt][nt], 0, 0, 0);
        acc[mt][nt] = __builtin_amdgcn_mfma_f32_16x16x32_bf16(a1, bf[1][nt], acc[mt][nt], 0, 0, 0);
        acc[mt][nt] = __builtin_amdgcn_mfma_f32_16x16x32_bf16(a2, bf[0][nt], acc[mt][nt], 0, 0, 0);
        acc[mt][nt] = __builtin_amdgcn_mfma_f32_16x16x32_bf16(a2, bf[1][nt], acc[mt][nt], 0, 0, 0);
        acc[mt][nt] = __builtin_amdgcn_mfma_f32_16x16x32_bf16(a1, bf[2][nt], acc[mt][nt], 0, 0, 0);
        acc[mt][nt] = __builtin_amdgcn_mfma_f32_16x16x32_bf16(a3, bf[0][nt], acc[mt][nt], 0, 0, 0);
      }
    }
    __syncthreads();
  }

  float bb[4];
  #pragma unroll
  for (int nt = 0; nt < 4; ++nt) bb[nt] = bias[n0 + wc + nt * 16 + c];

  #pragma unroll
  for (int mt = 0; mt < 4; ++mt) {
    #pragma unroll
    for (int nt = 0; nt < 4; ++nt) {
      const int n = n0 + wc + nt * 16 + c;
      const int h = n >> 6, d = n & 63;
      #pragma unroll
      for (int r = 0; r < 4; ++r) {
        const int m = m0 + wr + mt * 16 + G * 4 + r;
        const int b = m >> 12, l = m & (LSEQ - 1);
        Y[((size_t)((b << 4) + h) * LSEQ + l) * HD + d] = acc[mt][nt][r] + bb[nt];
      }
    }
  }
}

// ---------------------------------------------------------------------------
// bf16 MFMA GEMM: Y = Xb @ Wb^T + bias.  128x128 tile, BK=32, 4 waves.
// MODE 0: bf16 out, split-head [bh][key][d] (K projection)
// MODE 1: fp32 out, row-major [M][1024]   (final output GEMM)
// MODE 2: bf16 out, TRANSPOSED per-head [bh*64+d][4096] (V projection),
//         via LDS-staged transpose for coalesced stores.
// ---------------------------------------------------------------------------
template<int MODE>
__global__ __launch_bounds__(256) void gemm_bf16(
    const u16* __restrict__ Xb, const u16* __restrict__ Wb,
    const float* __restrict__ bias, void* __restrict__ Yout)
{
  __shared__ u16 As[128 * 32];
  __shared__ u16 Bs[128 * 32];
  const int tid = threadIdx.x;
  const int m0 = blockIdx.x * 128, n0 = blockIdx.y * 128;
  const int wid = tid >> 6, lane = tid & 63;
  const int wr = (wid >> 1) * 64, wc = (wid & 1) * 64;
  const int c = lane & 15, G = lane >> 4;

  f32x4 acc[4][4];
  #pragma unroll
  for (int mt = 0; mt < 4; ++mt)
    #pragma unroll
    for (int nt = 0; nt < 4; ++nt)
      acc[mt][nt] = (f32x4){0.f, 0.f, 0.f, 0.f};

  for (int k0 = 0; k0 < DM; k0 += 32) {
    #pragma unroll
    for (int rr = 0; rr < 2; ++rr) {
      const int id = tid + rr * 256;
      const int row = id >> 2, kc = id & 3;
      short8v a = *reinterpret_cast<const short8v*>(Xb + (size_t)(m0 + row) * DM + k0 + kc * 8);
      short8v b = *reinterpret_cast<const short8v*>(Wb + (size_t)(n0 + row) * DM + k0 + kc * 8);
      const int e = (row * 32 + kc * 8) ^ ((row & 7) << 3);
      *reinterpret_cast<short8v*>(As + e) = a;
      *reinterpret_cast<short8v*>(Bs + e) = b;
    }
    __syncthreads();

    short8v af[4], bf[4];
    #pragma unroll
    for (int mt = 0; mt < 4; ++mt) {
      const int m = wr + mt * 16 + c;
      af[mt] = *reinterpret_cast<const short8v*>(As + ((m * 32 + G * 8) ^ ((m & 7) << 3)));
      const int n = wc + mt * 16 + c;
      bf[mt] = *reinterpret_cast<const short8v*>(Bs + ((n * 32 + G * 8) ^ ((n & 7) << 3)));
    }
    #pragma unroll
    for (int mt = 0; mt < 4; ++mt)
      #pragma unroll
      for (int nt = 0; nt < 4; ++nt)
        acc[mt][nt] = __builtin_amdgcn_mfma_f32_16x16x32_bf16(af[mt], bf[nt], acc[mt][nt], 0, 0, 0);
    __syncthreads();
  }

  float bb[4];
  #pragma unroll
  for (int nt = 0; nt < 4; ++nt) bb[nt] = bias[n0 + wc + nt * 16 + c];

  if constexpr (MODE == 2) {
    // stage bf16 result transposed in LDS: T[n][m_local], stride 136 u16
    __shared__ u16 T[128 * 136];
    #pragma unroll
    for (int mt = 0; mt < 4; ++mt) {
      #pragma unroll
      for (int nt = 0; nt < 4; ++nt) {
        const int n = wc + nt * 16 + c;
        const int mloc = wr + mt * 16 + G * 4;
        short4v pv;
        #pragma unroll
        for (int r = 0; r < 4; ++r) pv[r] = (short)f2bf(acc[mt][nt][r] + bb[nt]);
        *reinterpret_cast<short4v*>(T + n * 136 + mloc) = pv;
      }
    }
    __syncthreads();
    u16* Y = (u16*)Yout;
    const int bb2 = m0 >> 12;        // batch
    const int ml0 = m0 & (LSEQ - 1);
    #pragma unroll
    for (int uu = 0; uu < 8; ++uu) {
      const int u = uu * 256 + tid;
      const int n = u >> 4, kg = u & 15;
      short8v vvv = *reinterpret_cast<const short8v*>(T + n * 136 + kg * 8);
      const int h = (n0 + n) >> 6, d = (n0 + n) & 63;
      *reinterpret_cast<short8v*>(
          Y + ((size_t)((bb2 << 4) + h) * HD + d) * LSEQ + ml0 + kg * 8) = vvv;
    }
  } else {
    #pragma unroll
    for (int mt = 0; mt < 4; ++mt) {
      #pragma unroll
      for (int nt = 0; nt < 4; ++nt) {
        const int n = n0 + wc + nt * 16 + c;
        #pragma unroll
        for (int r = 0; r < 4; ++r) {
          const int m = m0 + wr + mt * 16 + G * 4 + r;
          const float val = acc[mt][nt][r] + bb[nt];
          if (MODE == 0) {
            const int b = m >> 12, l = m & (LSEQ - 1), h = n >> 6, d = n & 63;
            u16* Y = (u16*)Yout;
            Y[((size_t)((b << 4) + h) * LSEQ + l) * HD + d] = f2bf(val);
          } else {
            float* Y = (float*)Yout;
            Y[(size_t)m * DM + n] = val;
          }
        }
      }
    }
  }
}

// ---------------------------------------------------------------------------
// Per-row squared L2 norms of Q (fp32).  One row (64 floats) per thread.
// ---------------------------------------------------------------------------
__global__ __launch_bounds__(256) void norms_kernel(
    const float* __restrict__ Q, float* __restrict__ norms)
{
  const int r = blockIdx.x * 256 + threadIdx.x;
  const float4* row = reinterpret_cast<const float4*>(Q + (size_t)r * HD);
  float s = 0.f;
  #pragma unroll
  for (int i = 0; i < 16; ++i) {
    float4 v = row[i];
    s += v.x * v.x + v.y * v.y + v.z * v.z + v.w * v.w;
  }
  norms[r] = s;
}

// ---------------------------------------------------------------------------
// Per-bh top-TOPU selection (set only) -- byte-radix select + stable compact.
// ---------------------------------------------------------------------------
__global__ __launch_bounds__(1024) void select_topk(
    const float* __restrict__ norms, int* __restrict__ top_idx)
{
  __shared__ unsigned int keys[LSEQ];
  __shared__ unsigned int hist[256];
  __shared__ unsigned int wsums[16];
  __shared__ unsigned int sh_b, sh_above;

  const int tid = threadIdx.x;
  const int bh = blockIdx.x;

  for (int l = tid; l < LSEQ; l += 1024)
    keys[l] = __float_as_uint(norms[bh * LSEQ + l]);
  __syncthreads();

  unsigned int prefix = 0, rem = TOPU, total_gt = 0;
  for (int shift = 24; shift >= 0; shift -= 8) {
    if (tid < 256) hist[tid] = 0;
    __syncthreads();
    for (int l = tid; l < LSEQ; l += 1024) {
      const unsigned int k = keys[l];
      const bool in = (shift == 24) || ((k >> (shift + 8)) == prefix);
      if (in) atomicAdd(&hist[(k >> shift) & 255], 1);
    }
    __syncthreads();
    if (tid == 0) {
      unsigned int cum = 0; int b = 255;
      for (; b > 0; --b) {
        const unsigned int h = hist[b];
        if (cum + h >= rem) break;
        cum += h;
      }
      sh_b = (unsigned int)b; sh_above = cum;
    }
    __syncthreads();
    prefix = (prefix << 8) | sh_b;
    total_gt += sh_above;
    rem -= sh_above;
    __syncthreads();
  }
  const unsigned int T = prefix;

  const int lane = tid & 63, wv = tid >> 6;
  const int l0 = tid * 4;

  {
    unsigned int flags = 0; int cnt = 0;
    #pragma unroll
    for (int j = 0; j < 4; ++j)
      if (keys[l0 + j] > T) { flags |= 1u << j; ++cnt; }
    int incl = cnt;
    #pragma unroll
    for (int off = 1; off < 64; off <<= 1) {
      int nv = __shfl_up(incl, off);
      if (lane >= off) incl += nv;
    }
    if (lane == 63) wsums[wv] = (unsigned int)incl;
    __syncthreads();
    if (tid == 0) {
      unsigned int run = 0;
      for (int w = 0; w < 16; ++w) { unsigned int t = wsums[w]; wsums[w] = run; run += t; }
    }
    __syncthreads();
    unsigned int pos = wsums[wv] + (unsigned int)(incl - cnt);
    #pragma unroll
    for (int j = 0; j < 4; ++j)
      if (flags & (1u << j)) top_idx[bh * TOPU + (pos++)] = l0 + j;
  }
  __syncthreads();

  {
    unsigned int flags = 0; int cnt = 0;
    #pragma unroll
    for (int j = 0; j < 4; ++j)
      if (keys[l0 + j] == T) { flags |= 1u << j; ++cnt; }
    int incl = cnt;
    #pragma unroll
    for (int off = 1; off < 64; off <<= 1) {
      int nv = __shfl_up(incl, off);
      if (lane >= off) incl += nv;
    }
    if (lane == 63) wsums[wv] = (unsigned int)incl;
    __syncthreads();
    if (tid == 0) {
      unsigned int run = 0;
      for (int w = 0; w < 16; ++w) { unsigned int t = wsums[w]; wsums[w] = run; run += t; }
    }
    __syncthreads();
    unsigned int r0 = wsums[wv] + (unsigned int)(incl - cnt);
    #pragma unroll
    for (int j = 0; j < 4; ++j)
      if (flags & (1u << j)) {
        if (r0 < rem) top_idx[bh * TOPU + total_gt + r0] = l0 + j;
        ++r0;
      }
  }
}

// ---------------------------------------------------------------------------
// MFMA flash attention, restructured:
//   swapped QK^T (lane holds P[k][q=c]) -> in-lane softmax, vector P stores,
//   V pre-transposed in global (VgT[bh*64+d][4096]) -> no in-kernel transpose,
//   KVBLK=128, 2 barriers / 128 keys, conflict-free LDS patterns,
//   XCD-swizzled 1D grid.
// ---------------------------------------------------------------------------
__global__ __launch_bounds__(256) void attn_mfma(
    const float* __restrict__ Qf, const u16* __restrict__ Kg,
    const u16* __restrict__ VgT, const int* __restrict__ tix,
    u16* __restrict__ O1b)
{
  __shared__ u16 Kc[128 * 64];      // [key][d], d-granule ^= key&7
  __shared__ u16 Vt[64 * 128];      // [d][key], k-granule ^= d&7
  __shared__ u16 Pt[4][16 * 136];   // per-wave [q][k], stride 136

  const int tid = threadIdx.x;
  const int wid = tid >> 6, lane = tid & 63;
  const int c = lane & 15, G = lane >> 4;

  // XCD swizzle: 13 q-blocks of each bh stay on one XCD (xcd = dispatch % 8)
  const int l = blockIdx.x;
  const int bh = ((l >> 3) / 13) * 8 + (l & 7);
  const int qb = (l >> 3) % 13;

  const size_t bhL = (size_t)bh * LSEQ;
  const int rglob = qb * 64 + wid * 16 + c;
  const int rowidx = (rglob < TOPU) ? tix[bh * TOPU + rglob] : -1;

  // Q fragment: lane holds Q[q=c][d = kf*32 + G*8 + j] * scale
  short8v qf[2];
  #pragma unroll
  for (int kf = 0; kf < 2; ++kf) {
    if (rowidx >= 0) {
      const float* qp = Qf + (bhL + rowidx) * HD + kf * 32 + G * 8;
      const float4 x0 = *reinterpret_cast<const float4*>(qp);
      const float4 x1 = *reinterpret_cast<const float4*>(qp + 4);
      short8v v;
      v[0] = (short)f2bf(x0.x * 0.125f); v[1] = (short)f2bf(x0.y * 0.125f);
      v[2] = (short)f2bf(x0.z * 0.125f); v[3] = (short)f2bf(x0.w * 0.125f);
      v[4] = (short)f2bf(x1.x * 0.125f); v[5] = (short)f2bf(x1.y * 0.125f);
      v[6] = (short)f2bf(x1.z * 0.125f); v[7] = (short)f2bf(x1.w * 0.125f);
      qf[kf] = v;
    } else {
      short8v v;
      #pragma unroll
      for (int j = 0; j < 8; ++j) v[j] = 0;
      qf[kf] = v;
    }
  }

  float m = -1e30f, lsum = 0.f;
  f32x4 oacc[4];
  #pragma unroll
  for (int dt = 0; dt < 4; ++dt) oacc[dt] = (f32x4){0.f, 0.f, 0.f, 0.f};

  for (int t = 0; t < LSEQ / 128; ++t) {
    // ---- stage K [key][d] and V^T [d][key] (both swizzled, conflict-free) ----
    #pragma unroll
    for (int uu = 0; uu < 4; ++uu) {
      const int u = uu * 256 + tid;
      const int key = u >> 3, dg = u & 7;
      short8v kv = *reinterpret_cast<const short8v*>(
          Kg + (bhL + t * 128 + key) * HD + dg * 8);
      *reinterpret_cast<short8v*>(Kc + key * 64 + ((dg ^ (key & 7)) << 3)) = kv;
      const int d = u >> 4, kg = u & 15;
      short8v vv = *reinterpret_cast<const short8v*>(
          VgT + ((size_t)bh * HD + d) * LSEQ + t * 128 + kg * 8);
      *reinterpret_cast<short8v*>(Vt + d * 128 + ((kg ^ (d & 7)) << 3)) = vv;
    }
    __syncthreads();

    // ---- swapped QK^T: sacc[kt] reg r = S[key = kt*16 + G*4 + r][q = c] ----
    f32x4 sacc[8];
    __builtin_amdgcn_s_setprio(1);
    #pragma unroll
    for (int kt = 0; kt < 8; ++kt) {
      const int key = kt * 16 + c;
      short8v kb0 = *reinterpret_cast<const short8v*>(
          Kc + key * 64 + (((0 + G) ^ (key & 7)) << 3));
      short8v kb1 = *reinterpret_cast<const short8v*>(
          Kc + key * 64 + (((4 + G) ^ (key & 7)) << 3));
      f32x4 s = (f32x4){0.f, 0.f, 0.f, 0.f};
      s = __builtin_amdgcn_mfma_f32_16x16x32_bf16(kb0, qf[0], s, 0, 0, 0);
      s = __builtin_amdgcn_mfma_f32_16x16x32_bf16(kb1, qf[1], s, 0, 0, 0);
      sacc[kt] = s;
    }
    __builtin_amdgcn_s_setprio(0);

    // ---- online softmax: per lane, one q-row (q = c) ----
    float smax = -1e30f;
    #pragma unroll
    for (int kt = 0; kt < 8; ++kt) {
      float a0 = fmaxf(sacc[kt][0], sacc[kt][1]);
      float a1 = fmaxf(sacc[kt][2], sacc[kt][3]);
      smax = fmaxf(smax, fmaxf(a0, a1));
    }
    smax = fmaxf(smax, __shfl_xor(smax, 16));
    smax = fmaxf(smax, __shfl_xor(smax, 32));
    const float mnew = fmaxf(m, smax);
    const float corr = __expf(m - mnew);
    float ssum = 0.f;
    #pragma unroll
    for (int kt = 0; kt < 8; ++kt) {
      float p0 = __expf(sacc[kt][0] - mnew);
      float p1 = __expf(sacc[kt][1] - mnew);
      float p2 = __expf(sacc[kt][2] - mnew);
      float p3 = __expf(sacc[kt][3] - mnew);
      ssum += (p0 + p1) + (p2 + p3);
      short4v pv;
      pv[0] = (short)f2bf(p0); pv[1] = (short)f2bf(p1);
      pv[2] = (short)f2bf(p2); pv[3] = (short)f2bf(p3);
      *reinterpret_cast<short4v*>(&Pt[wid][c * 136 + kt * 16 + G * 4]) = pv;
    }
    ssum += __shfl_xor(ssum, 16);
    ssum += __shfl_xor(ssum, 32);
    lsum = lsum * corr + ssum;
    m = mnew;
    #pragma unroll
    for (int dt = 0; dt < 4; ++dt) oacc[dt] *= corr;

    // ---- PV: O^T += V^T @ P (Pt wave-private; Vt staged above) ----
    __builtin_amdgcn_s_setprio(1);
    #pragma unroll
    for (int kf = 0; kf < 4; ++kf) {
      short8v pf = *reinterpret_cast<const short8v*>(
          &Pt[wid][c * 136 + kf * 32 + G * 8]);
      #pragma unroll
      for (int dt = 0; dt < 4; ++dt) {
        const int d = dt * 16 + c;
        short8v vf = *reinterpret_cast<const short8v*>(
            Vt + d * 128 + (((kf * 4 + G) ^ (d & 7)) << 3));
        oacc[dt] = __builtin_amdgcn_mfma_f32_16x16x32_bf16(vf, pf, oacc[dt], 0, 0, 0);
      }
    }
    __builtin_amdgcn_s_setprio(0);
    __syncthreads();
  }

  // ---- epilogue: lane owns q=c entirely; oacc[dt] reg r = O[q][dt*16+G*4+r] ----
  const float linv = 1.0f / lsum;
  if (rowidx >= 0) {
    const int b = bh >> 4, h = bh & 15;
    u16* base = O1b + (size_t)(b * LSEQ + rowidx) * DM + h * HD;
    #pragma unroll
    for (int dt = 0; dt < 4; ++dt) {
      short4v o;
      o[0] = (short)f2bf(oacc[dt][0] * linv);
      o[1] = (short)f2bf(oacc[dt][1] * linv);
      o[2] = (short)f2bf(oacc[dt][2] * linv);
      o[3] = (short)f2bf(oacc[dt][3] * linv);
      *reinterpret_cast<short4v*>(base + dt * 16 + G * 4) = o;
    }
  }
}

// ---------------------------------------------------------------------------
extern "C" void kernel_launch(void* const* d_in, const int* in_sizes, int n_in,
                              void* d_out, int out_size, void* d_ws, size_t ws_size,
                              hipStream_t stream) {
  const float* x  = (const float*)d_in[0];
  const float* Wq = (const float*)d_in[1];
  const float* bq = (const float*)d_in[2];
  const float* Wk = (const float*)d_in[3];
  const float* bk = (const float*)d_in[4];
  const float* Wv = (const float*)d_in[5];
  const float* bv = (const float*)d_in[6];
  const float* Wo = (const float*)d_in[7];
  const float* bo = (const float*)d_in[8];
  float* out = (float*)d_out;

  char* w = (char*)d_ws;
  float* Qb = (float*)w;  w += (size_t)BHT * LSEQ * HD * 4;    // 32 MB fp32
  u16* x1   = (u16*)w;    w += (size_t)MROWS * DM * 2;         // 16 MB
  u16* x2   = (u16*)w;    w += (size_t)MROWS * DM * 2;         // 16 MB -> later O1b
  u16* x3   = (u16*)w;    w += (size_t)MROWS * DM * 2;         // 16 MB -> later Kb
  u16* VgT  = (u16*)w;    w += (size_t)BHT * HD * LSEQ * 2;    // 16 MB (V^T)
  u16* Wkb  = (u16*)w;    w += (size_t)DM * DM * 2;            // 2 MB
  u16* Wvb  = (u16*)w;    w += (size_t)DM * DM * 2;
  u16* Wob  = (u16*)w;    w += (size_t)DM * DM * 2;
  u16* wq1  = (u16*)w;    w += (size_t)DM * DM * 2;            // -> later norms
  u16* wq2  = (u16*)w;    w += (size_t)DM * DM * 2;            // -> later tix
  u16* wq3  = (u16*)w;    w += (size_t)DM * DM * 2;

  u16*   O1b   = x2;
  u16*   Kb    = x3;
  float* norms = (float*)wq1;
  int*   tix   = (int*)wq2;

  split3_kernel<<<4096, 256, 0, stream>>>(x,  x1,  x2,  x3,  MROWS * DM / 8);
  split3_kernel<<<512,  256, 0, stream>>>(Wq, wq1, wq2, wq3, DM * DM / 8);
  conv_bf16<<<512, 256, 0, stream>>>(Wk, Wkb, DM * DM / 8);
  conv_bf16<<<512, 256, 0, stream>>>(Wv, Wvb, DM * DM / 8);
  conv_bf16<<<512, 256, 0, stream>>>(Wo, Wob, DM * DM / 8);

  gemm_q_split<<<dim3(MROWS / 128, DM / 128), 256, 0, stream>>>(
      x1, x2, x3, wq1, wq2, wq3, bq, Qb);

  gemm_bf16<0><<<dim3(MROWS / 128, DM / 128), 256, 0, stream>>>(x1, Wkb, bk, (void*)Kb);
  gemm_bf16<2><<<dim3(MROWS / 128, DM / 128), 256, 0, stream>>>(x1, Wvb, bv, (void*)VgT);

  norms_kernel<<<BHT * LSEQ / 256, 256, 0, stream>>>(Qb, norms);
  select_topk<<<BHT, 1024, 0, stream>>>(norms, tix);

  hipMemsetAsync(O1b, 0, (size_t)MROWS * DM * 2, stream);

  attn_mfma<<<416, 256, 0, stream>>>(Qb, Kb, VgT, tix, O1b);

  gemm_bf16<1><<<dim3(MROWS / 128, DM / 128), 256, 0, stream>>>(O1b, Wob, bo, (void*)out);
}

// Round 5
// 319.838 us; speedup vs baseline: 6.4277x; 1.0319x over previous
//
#include <hip/hip_runtime.h>
#include <cstddef>
#include <cstdint>

constexpr int LSEQ = 4096;
constexpr int DM   = 1024;
constexpr int HD   = 64;
constexpr int BHT  = 32;     // B*H
constexpr int TOPU = 819;
constexpr int MROWS = 8192;  // B*L

typedef unsigned short u16;
typedef __attribute__((ext_vector_type(8))) short short8v;  // 8 bf16 (4 VGPR)
typedef __attribute__((ext_vector_type(4))) short short4v;  // 4 bf16 (8B)
typedef __attribute__((ext_vector_type(4))) float f32x4;

__device__ __forceinline__ u16 f2bf(float f) {
  uint32_t u = __float_as_uint(f);
  u += 0x7fffu + ((u >> 16) & 1u);   // RNE
  return (u16)(u >> 16);
}
__device__ __forceinline__ float bf2f(u16 h) {
  return __uint_as_float(((uint32_t)h) << 16);
}

// async 16B global -> LDS (DMA; no VGPR round trip).  LDS dest must be
// wave-uniform base; HW adds lane*16.
__device__ __forceinline__ void gl16(const void* g, void* l) {
  __builtin_amdgcn_global_load_lds(
      (const __attribute__((address_space(1))) void*)g,
      (__attribute__((address_space(3))) void*)l, 16, 0, 0);
}

// Inverse of the LDS swizzle e = (R*32 + C*8) ^ ((R&7)<<3) for linear slot S
// (u16 units): gives the (row R, k-granule C) whose data lives at slot S.
__device__ __forceinline__ void inv_swz(int S, int& R, int& C) {
  const int R0 = ((S >> 5) ^ (S >> 7)) & 1;
  const int R1 = (S >> 6) & 1;
  R = ((S >> 6) << 1) | R0;
  C = (((S >> 3) & 1) ^ R0) | ((((S >> 4) & 1) ^ R1) << 1);
}

// ---------------------------------------------------------------------------
// fp32 -> 3-piece bf16 split (x ~= p1+p2+p3 to ~2^-24 rel).  8 elems/thread.
// ---------------------------------------------------------------------------
__global__ __launch_bounds__(256) void split3_kernel(
    const float* __restrict__ src, u16* __restrict__ p1,
    u16* __restrict__ p2, u16* __restrict__ p3, int n8)
{
  int i = blockIdx.x * 256 + threadIdx.x;
  if (i >= n8) return;
  const float4 a = *reinterpret_cast<const float4*>(src + (size_t)i * 8);
  const float4 b = *reinterpret_cast<const float4*>(src + (size_t)i * 8 + 4);
  float e[8] = {a.x, a.y, a.z, a.w, b.x, b.y, b.z, b.w};
  short8v v1, v2, v3;
  #pragma unroll
  for (int j = 0; j < 8; ++j) {
    u16 h1 = f2bf(e[j]);        float r1 = e[j] - bf2f(h1);
    u16 h2 = f2bf(r1);          float r2 = r1 - bf2f(h2);
    u16 h3 = f2bf(r2);
    v1[j] = (short)h1; v2[j] = (short)h2; v3[j] = (short)h3;
  }
  *reinterpret_cast<short8v*>(p1 + (size_t)i * 8) = v1;
  *reinterpret_cast<short8v*>(p2 + (size_t)i * 8) = v2;
  *reinterpret_cast<short8v*>(p3 + (size_t)i * 8) = v3;
}

// ---------------------------------------------------------------------------
// fp32 -> bf16 bulk convert (8 elems / thread)
// ---------------------------------------------------------------------------
__global__ __launch_bounds__(256) void conv_bf16(
    const float* __restrict__ src, u16* __restrict__ dst, int n8)
{
  int i = blockIdx.x * 256 + threadIdx.x;
  if (i >= n8) return;
  const float4 a = *reinterpret_cast<const float4*>(src + (size_t)i * 8);
  const float4 b = *reinterpret_cast<const float4*>(src + (size_t)i * 8 + 4);
  short8v v;
  v[0] = (short)f2bf(a.x); v[1] = (short)f2bf(a.y);
  v[2] = (short)f2bf(a.z); v[3] = (short)f2bf(a.w);
  v[4] = (short)f2bf(b.x); v[5] = (short)f2bf(b.y);
  v[6] = (short)f2bf(b.z); v[7] = (short)f2bf(b.w);
  *reinterpret_cast<short8v*>(dst + (size_t)i * 8) = v;
}

// ---------------------------------------------------------------------------
// Q projection at fp32 accuracy via 3-piece split-bf16 MFMA (6 products).
// 128x128 tile, BK=32, 4 waves; staging via global_load_lds (linear dest,
// inverse-swizzled source); fp32 output in split-head layout.
// ---------------------------------------------------------------------------
__global__ __launch_bounds__(256) void gemm_q_split(
    const u16* __restrict__ X1, const u16* __restrict__ X2, const u16* __restrict__ X3,
    const u16* __restrict__ W1, const u16* __restrict__ W2, const u16* __restrict__ W3,
    const float* __restrict__ bias, float* __restrict__ Y)
{
  __shared__ u16 As[3][128 * 32];
  __shared__ u16 Bs[3][128 * 32];
  const int tid = threadIdx.x;
  const int m0 = blockIdx.x * 128, n0 = blockIdx.y * 128;
  const int wid = tid >> 6, lane = tid & 63;
  const int wr = (wid >> 1) * 64, wc = (wid & 1) * 64;
  const int c = lane & 15, G = lane >> 4;

  int Rr[2], Cr[2];
  #pragma unroll
  for (int rr = 0; rr < 2; ++rr) inv_swz((tid + rr * 256) * 8, Rr[rr], Cr[rr]);

  f32x4 acc[4][4];
  #pragma unroll
  for (int mt = 0; mt < 4; ++mt)
    #pragma unroll
    for (int nt = 0; nt < 4; ++nt)
      acc[mt][nt] = (f32x4){0.f, 0.f, 0.f, 0.f};

  for (int k0 = 0; k0 < DM; k0 += 32) {
    #pragma unroll
    for (int rr = 0; rr < 2; ++rr) {
      const size_t goA = (size_t)(m0 + Rr[rr]) * DM + k0 + Cr[rr] * 8;
      const size_t goB = (size_t)(n0 + Rr[rr]) * DM + k0 + Cr[rr] * 8;
      const int lb = wid * 512 + rr * 2048;
      gl16(X1 + goA, &As[0][lb]);
      gl16(X2 + goA, &As[1][lb]);
      gl16(X3 + goA, &As[2][lb]);
      gl16(W1 + goB, &Bs[0][lb]);
      gl16(W2 + goB, &Bs[1][lb]);
      gl16(W3 + goB, &Bs[2][lb]);
    }
    __syncthreads();

    short8v bf[3][4];
    #pragma unroll
    for (int nt = 0; nt < 4; ++nt) {
      const int n = wc + nt * 16 + c;
      const int eo = (n * 32 + G * 8) ^ ((n & 7) << 3);
      bf[0][nt] = *reinterpret_cast<const short8v*>(&Bs[0][eo]);
      bf[1][nt] = *reinterpret_cast<const short8v*>(&Bs[1][eo]);
      bf[2][nt] = *reinterpret_cast<const short8v*>(&Bs[2][eo]);
    }
    #pragma unroll
    for (int mt = 0; mt < 4; ++mt) {
      const int m = wr + mt * 16 + c;
      const int eo = (m * 32 + G * 8) ^ ((m & 7) << 3);
      short8v a1 = *reinterpret_cast<const short8v*>(&As[0][eo]);
      short8v a2 = *reinterpret_cast<const short8v*>(&As[1][eo]);
      short8v a3 = *reinterpret_cast<const short8v*>(&As[2][eo]);
      #pragma unroll
      for (int nt = 0; nt < 4; ++nt) {
        acc[mt][nt] = __builtin_amdgcn_mfma_f32_16x16x32_bf16(a1, bf[0][nt], acc[mt][nt], 0, 0, 0);
        acc[mt][nt] = __builtin_amdgcn_mfma_f32_16x16x32_bf16(a1, bf[1][nt], acc[mt][nt], 0, 0, 0);
        acc[mt][nt] = __builtin_amdgcn_mfma_f32_16x16x32_bf16(a2, bf[0][nt], acc[mt][nt], 0, 0, 0);
        acc[mt][nt] = __builtin_amdgcn_mfma_f32_16x16x32_bf16(a2, bf[1][nt], acc[mt][nt], 0, 0, 0);
        acc[mt][nt] = __builtin_amdgcn_mfma_f32_16x16x32_bf16(a1, bf[2][nt], acc[mt][nt], 0, 0, 0);
        acc[mt][nt] = __builtin_amdgcn_mfma_f32_16x16x32_bf16(a3, bf[0][nt], acc[mt][nt], 0, 0, 0);
      }
    }
    __syncthreads();
  }

  float bb[4];
  #pragma unroll
  for (int nt = 0; nt < 4; ++nt) bb[nt] = bias[n0 + wc + nt * 16 + c];

  #pragma unroll
  for (int mt = 0; mt < 4; ++mt) {
    #pragma unroll
    for (int nt = 0; nt < 4; ++nt) {
      const int n = n0 + wc + nt * 16 + c;
      const int h = n >> 6, d = n & 63;
      #pragma unroll
      for (int r = 0; r < 4; ++r) {
        const int m = m0 + wr + mt * 16 + G * 4 + r;
        const int b = m >> 12, l = m & (LSEQ - 1);
        Y[((size_t)((b << 4) + h) * LSEQ + l) * HD + d] = acc[mt][nt][r] + bb[nt];
      }
    }
  }
}

// ---------------------------------------------------------------------------
// bf16 MFMA GEMM: Y = Xb @ Wb^T + bias.  128x128 tile, BK=32, 4 waves,
// global_load_lds staging.
// MODE 0: bf16 out, split-head [bh][key][d] (K projection)
// MODE 1: fp32 out, row-major [M][1024]   (final output GEMM)
// MODE 2: bf16 out, TRANSPOSED per-head [bh*64+d][4096] (V projection)
// ---------------------------------------------------------------------------
template<int MODE>
__global__ __launch_bounds__(256) void gemm_bf16(
    const u16* __restrict__ Xb, const u16* __restrict__ Wb,
    const float* __restrict__ bias, void* __restrict__ Yout)
{
  __shared__ u16 As[128 * 32];
  __shared__ u16 Bs[128 * 32];
  const int tid = threadIdx.x;
  const int m0 = blockIdx.x * 128, n0 = blockIdx.y * 128;
  const int wid = tid >> 6, lane = tid & 63;
  const int wr = (wid >> 1) * 64, wc = (wid & 1) * 64;
  const int c = lane & 15, G = lane >> 4;

  int Rr[2], Cr[2];
  #pragma unroll
  for (int rr = 0; rr < 2; ++rr) inv_swz((tid + rr * 256) * 8, Rr[rr], Cr[rr]);

  f32x4 acc[4][4];
  #pragma unroll
  for (int mt = 0; mt < 4; ++mt)
    #pragma unroll
    for (int nt = 0; nt < 4; ++nt)
      acc[mt][nt] = (f32x4){0.f, 0.f, 0.f, 0.f};

  for (int k0 = 0; k0 < DM; k0 += 32) {
    #pragma unroll
    for (int rr = 0; rr < 2; ++rr) {
      const size_t goA = (size_t)(m0 + Rr[rr]) * DM + k0 + Cr[rr] * 8;
      const size_t goB = (size_t)(n0 + Rr[rr]) * DM + k0 + Cr[rr] * 8;
      const int lb = wid * 512 + rr * 2048;
      gl16(Xb + goA, As + lb);
      gl16(Wb + goB, Bs + lb);
    }
    __syncthreads();

    short8v af[4], bf[4];
    #pragma unroll
    for (int mt = 0; mt < 4; ++mt) {
      const int m = wr + mt * 16 + c;
      af[mt] = *reinterpret_cast<const short8v*>(As + ((m * 32 + G * 8) ^ ((m & 7) << 3)));
      const int n = wc + mt * 16 + c;
      bf[mt] = *reinterpret_cast<const short8v*>(Bs + ((n * 32 + G * 8) ^ ((n & 7) << 3)));
    }
    #pragma unroll
    for (int mt = 0; mt < 4; ++mt)
      #pragma unroll
      for (int nt = 0; nt < 4; ++nt)
        acc[mt][nt] = __builtin_amdgcn_mfma_f32_16x16x32_bf16(af[mt], bf[nt], acc[mt][nt], 0, 0, 0);
    __syncthreads();
  }

  float bb[4];
  #pragma unroll
  for (int nt = 0; nt < 4; ++nt) bb[nt] = bias[n0 + wc + nt * 16 + c];

  if constexpr (MODE == 2) {
    __shared__ u16 T[128 * 136];
    #pragma unroll
    for (int mt = 0; mt < 4; ++mt) {
      #pragma unroll
      for (int nt = 0; nt < 4; ++nt) {
        const int n = wc + nt * 16 + c;
        const int mloc = wr + mt * 16 + G * 4;
        short4v pv;
        #pragma unroll
        for (int r = 0; r < 4; ++r) pv[r] = (short)f2bf(acc[mt][nt][r] + bb[nt]);
        *reinterpret_cast<short4v*>(T + n * 136 + mloc) = pv;
      }
    }
    __syncthreads();
    u16* Y = (u16*)Yout;
    const int bb2 = m0 >> 12;
    const int ml0 = m0 & (LSEQ - 1);
    #pragma unroll
    for (int uu = 0; uu < 8; ++uu) {
      const int u = uu * 256 + tid;
      const int n = u >> 4, kg = u & 15;
      short8v vvv = *reinterpret_cast<const short8v*>(T + n * 136 + kg * 8);
      const int h = (n0 + n) >> 6, d = (n0 + n) & 63;
      *reinterpret_cast<short8v*>(
          Y + ((size_t)((bb2 << 4) + h) * HD + d) * LSEQ + ml0 + kg * 8) = vvv;
    }
  } else {
    #pragma unroll
    for (int mt = 0; mt < 4; ++mt) {
      #pragma unroll
      for (int nt = 0; nt < 4; ++nt) {
        const int n = n0 + wc + nt * 16 + c;
        #pragma unroll
        for (int r = 0; r < 4; ++r) {
          const int m = m0 + wr + mt * 16 + G * 4 + r;
          const float val = acc[mt][nt][r] + bb[nt];
          if (MODE == 0) {
            const int b = m >> 12, l = m & (LSEQ - 1), h = n >> 6, d = n & 63;
            u16* Y = (u16*)Yout;
            Y[((size_t)((b << 4) + h) * LSEQ + l) * HD + d] = f2bf(val);
          } else {
            float* Y = (float*)Yout;
            Y[(size_t)m * DM + n] = val;
          }
        }
      }
    }
  }
}

// ---------------------------------------------------------------------------
// Per-row squared L2 norms of Q (fp32).  One row (64 floats) per thread.
// ---------------------------------------------------------------------------
__global__ __launch_bounds__(256) void norms_kernel(
    const float* __restrict__ Q, float* __restrict__ norms)
{
  const int r = blockIdx.x * 256 + threadIdx.x;
  const float4* row = reinterpret_cast<const float4*>(Q + (size_t)r * HD);
  float s = 0.f;
  #pragma unroll
  for (int i = 0; i < 16; ++i) {
    float4 v = row[i];
    s += v.x * v.x + v.y * v.y + v.z * v.z + v.w * v.w;
  }
  norms[r] = s;
}

// ---------------------------------------------------------------------------
// Per-bh top-TOPU selection (set only) -- byte-radix select + stable compact.
// ---------------------------------------------------------------------------
__global__ __launch_bounds__(1024) void select_topk(
    const float* __restrict__ norms, int* __restrict__ top_idx)
{
  __shared__ unsigned int keys[LSEQ];
  __shared__ unsigned int hist[256];
  __shared__ unsigned int wsums[16];
  __shared__ unsigned int sh_b, sh_above;

  const int tid = threadIdx.x;
  const int bh = blockIdx.x;

  for (int l = tid; l < LSEQ; l += 1024)
    keys[l] = __float_as_uint(norms[bh * LSEQ + l]);
  __syncthreads();

  unsigned int prefix = 0, rem = TOPU, total_gt = 0;
  for (int shift = 24; shift >= 0; shift -= 8) {
    if (tid < 256) hist[tid] = 0;
    __syncthreads();
    for (int l = tid; l < LSEQ; l += 1024) {
      const unsigned int k = keys[l];
      const bool in = (shift == 24) || ((k >> (shift + 8)) == prefix);
      if (in) atomicAdd(&hist[(k >> shift) & 255], 1);
    }
    __syncthreads();
    if (tid == 0) {
      unsigned int cum = 0; int b = 255;
      for (; b > 0; --b) {
        const unsigned int h = hist[b];
        if (cum + h >= rem) break;
        cum += h;
      }
      sh_b = (unsigned int)b; sh_above = cum;
    }
    __syncthreads();
    prefix = (prefix << 8) | sh_b;
    total_gt += sh_above;
    rem -= sh_above;
    __syncthreads();
  }
  const unsigned int T = prefix;

  const int lane = tid & 63, wv = tid >> 6;
  const int l0 = tid * 4;

  {
    unsigned int flags = 0; int cnt = 0;
    #pragma unroll
    for (int j = 0; j < 4; ++j)
      if (keys[l0 + j] > T) { flags |= 1u << j; ++cnt; }
    int incl = cnt;
    #pragma unroll
    for (int off = 1; off < 64; off <<= 1) {
      int nv = __shfl_up(incl, off);
      if (lane >= off) incl += nv;
    }
    if (lane == 63) wsums[wv] = (unsigned int)incl;
    __syncthreads();
    if (tid == 0) {
      unsigned int run = 0;
      for (int w = 0; w < 16; ++w) { unsigned int t = wsums[w]; wsums[w] = run; run += t; }
    }
    __syncthreads();
    unsigned int pos = wsums[wv] + (unsigned int)(incl - cnt);
    #pragma unroll
    for (int j = 0; j < 4; ++j)
      if (flags & (1u << j)) top_idx[bh * TOPU + (pos++)] = l0 + j;
  }
  __syncthreads();

  {
    unsigned int flags = 0; int cnt = 0;
    #pragma unroll
    for (int j = 0; j < 4; ++j)
      if (keys[l0 + j] == T) { flags |= 1u << j; ++cnt; }
    int incl = cnt;
    #pragma unroll
    for (int off = 1; off < 64; off <<= 1) {
      int nv = __shfl_up(incl, off);
      if (lane >= off) incl += nv;
    }
    if (lane == 63) wsums[wv] = (unsigned int)incl;
    __syncthreads();
    if (tid == 0) {
      unsigned int run = 0;
      for (int w = 0; w < 16; ++w) { unsigned int t = wsums[w]; wsums[w] = run; run += t; }
    }
    __syncthreads();
    unsigned int r0 = wsums[wv] + (unsigned int)(incl - cnt);
    #pragma unroll
    for (int j = 0; j < 4; ++j)
      if (flags & (1u << j)) {
        if (r0 < rem) top_idx[bh * TOPU + total_gt + r0] = l0 + j;
        ++r0;
      }
  }
}

// ---------------------------------------------------------------------------
// MFMA flash attention, split-K (2 key-halves per (bh,qb)), fp32 partials.
// Grid 832 = 32bh x 13qb x 2ks, XCD-grouped.  Per block: 64 q-rows, 2048 keys.
// ---------------------------------------------------------------------------
__global__ __launch_bounds__(256) void attn_mfma(
    const float* __restrict__ Qf, const u16* __restrict__ Kg,
    const u16* __restrict__ VgT, const int* __restrict__ tix,
    float* __restrict__ Opart, float* __restrict__ MLpart)
{
  __shared__ u16 Kc[128 * 64];      // [key][d], d-granule ^= key&7
  __shared__ u16 Vt[64 * 128];      // [d][key], k-granule ^= d&7
  __shared__ u16 Pt[4][16 * 136];   // per-wave [q][k], stride 136

  const int tid = threadIdx.x;
  const int wid = tid >> 6, lane = tid & 63;
  const int c = lane & 15, G = lane >> 4;

  // XCD grouping: 832 = 8 xcd * 104; each xcd handles 4 bh entirely.
  const int l = blockIdx.x;
  const int grp = l >> 3;                  // 0..103
  const int bh = (grp / 26) * 8 + (l & 7);
  const int rem = grp % 26;
  const int qb = rem >> 1, ks = rem & 1;

  const size_t bhL = (size_t)bh * LSEQ;
  const int rglob = qb * 64 + wid * 16 + c;
  const int rowidx = (rglob < TOPU) ? tix[bh * TOPU + rglob] : -1;

  short8v qf[2];
  #pragma unroll
  for (int kf = 0; kf < 2; ++kf) {
    if (rowidx >= 0) {
      const float* qp = Qf + (bhL + rowidx) * HD + kf * 32 + G * 8;
      const float4 x0 = *reinterpret_cast<const float4*>(qp);
      const float4 x1 = *reinterpret_cast<const float4*>(qp + 4);
      short8v v;
      v[0] = (short)f2bf(x0.x * 0.125f); v[1] = (short)f2bf(x0.y * 0.125f);
      v[2] = (short)f2bf(x0.z * 0.125f); v[3] = (short)f2bf(x0.w * 0.125f);
      v[4] = (short)f2bf(x1.x * 0.125f); v[5] = (short)f2bf(x1.y * 0.125f);
      v[6] = (short)f2bf(x1.z * 0.125f); v[7] = (short)f2bf(x1.w * 0.125f);
      qf[kf] = v;
    } else {
      short8v v;
      #pragma unroll
      for (int j = 0; j < 8; ++j) v[j] = 0;
      qf[kf] = v;
    }
  }

  float m = -1e30f, lsum = 0.f;
  f32x4 oacc[4];
  #pragma unroll
  for (int dt = 0; dt < 4; ++dt) oacc[dt] = (f32x4){0.f, 0.f, 0.f, 0.f};

  const int ko0 = ks * (LSEQ / 2);
  for (int t = 0; t < LSEQ / 256; ++t) {
    const int ko = ko0 + t * 128;
    #pragma unroll
    for (int uu = 0; uu < 4; ++uu) {
      const int u = uu * 256 + tid;
      const int key = u >> 3, dg = u & 7;
      short8v kv = *reinterpret_cast<const short8v*>(
          Kg + (bhL + ko + key) * HD + dg * 8);
      *reinterpret_cast<short8v*>(Kc + key * 64 + ((dg ^ (key & 7)) << 3)) = kv;
      const int d = u >> 4, kg = u & 15;
      short8v vv = *reinterpret_cast<const short8v*>(
          VgT + ((size_t)bh * HD + d) * LSEQ + ko + kg * 8);
      *reinterpret_cast<short8v*>(Vt + d * 128 + ((kg ^ (d & 7)) << 3)) = vv;
    }
    __syncthreads();

    // swapped QK^T: sacc[kt] reg r = S[key = kt*16 + G*4 + r][q = c]
    f32x4 sacc[8];
    __builtin_amdgcn_s_setprio(1);
    #pragma unroll
    for (int kt = 0; kt < 8; ++kt) {
      const int key = kt * 16 + c;
      short8v kb0 = *reinterpret_cast<const short8v*>(
          Kc + key * 64 + (((0 + G) ^ (key & 7)) << 3));
      short8v kb1 = *reinterpret_cast<const short8v*>(
          Kc + key * 64 + (((4 + G) ^ (key & 7)) << 3));
      f32x4 s = (f32x4){0.f, 0.f, 0.f, 0.f};
      s = __builtin_amdgcn_mfma_f32_16x16x32_bf16(kb0, qf[0], s, 0, 0, 0);
      s = __builtin_amdgcn_mfma_f32_16x16x32_bf16(kb1, qf[1], s, 0, 0, 0);
      sacc[kt] = s;
    }
    __builtin_amdgcn_s_setprio(0);

    // online softmax: per lane, one q-row (q = c)
    float smax = -1e30f;
    #pragma unroll
    for (int kt = 0; kt < 8; ++kt) {
      float a0 = fmaxf(sacc[kt][0], sacc[kt][1]);
      float a1 = fmaxf(sacc[kt][2], sacc[kt][3]);
      smax = fmaxf(smax, fmaxf(a0, a1));
    }
    smax = fmaxf(smax, __shfl_xor(smax, 16));
    smax = fmaxf(smax, __shfl_xor(smax, 32));
    const float mnew = fmaxf(m, smax);
    const float corr = __expf(m - mnew);
    float ssum = 0.f;
    #pragma unroll
    for (int kt = 0; kt < 8; ++kt) {
      float p0 = __expf(sacc[kt][0] - mnew);
      float p1 = __expf(sacc[kt][1] - mnew);
      float p2 = __expf(sacc[kt][2] - mnew);
      float p3 = __expf(sacc[kt][3] - mnew);
      ssum += (p0 + p1) + (p2 + p3);
      short4v pv;
      pv[0] = (short)f2bf(p0); pv[1] = (short)f2bf(p1);
      pv[2] = (short)f2bf(p2); pv[3] = (short)f2bf(p3);
      *reinterpret_cast<short4v*>(&Pt[wid][c * 136 + kt * 16 + G * 4]) = pv;
    }
    ssum += __shfl_xor(ssum, 16);
    ssum += __shfl_xor(ssum, 32);
    lsum = lsum * corr + ssum;
    m = mnew;
    #pragma unroll
    for (int dt = 0; dt < 4; ++dt) oacc[dt] *= corr;

    // PV: O^T += V^T @ P
    __builtin_amdgcn_s_setprio(1);
    #pragma unroll
    for (int kf = 0; kf < 4; ++kf) {
      short8v pf = *reinterpret_cast<const short8v*>(
          &Pt[wid][c * 136 + kf * 32 + G * 8]);
      #pragma unroll
      for (int dt = 0; dt < 4; ++dt) {
        const int d = dt * 16 + c;
        short8v vf = *reinterpret_cast<const short8v*>(
            Vt + d * 128 + (((kf * 4 + G) ^ (d & 7)) << 3));
        oacc[dt] = __builtin_amdgcn_mfma_f32_16x16x32_bf16(vf, pf, oacc[dt], 0, 0, 0);
      }
    }
    __builtin_amdgcn_s_setprio(0);
    __syncthreads();
  }

  // partial epilogue: lane owns q=c; oacc[dt] reg r = O[q][dt*16+G*4+r]
  const int q = wid * 16 + c;
  const size_t pb = ((size_t)(bh * 13 + qb) * 2 + ks) * 64 + q;
  float* op = Opart + pb * 64;
  #pragma unroll
  for (int dt = 0; dt < 4; ++dt)
    *reinterpret_cast<f32x4*>(op + dt * 16 + G * 4) = oacc[dt];
  if (G == 0) {
    MLpart[pb * 2]     = m;
    MLpart[pb * 2 + 1] = lsum;
  }
}

// ---------------------------------------------------------------------------
// Flash split-K combine: O = (O0*c0 + O1*c1) / (l0*c0 + l1*c1), scatter bf16.
// Grid 416 = (bh,qb); thread: q = tid>>2, d-quarter = (tid&3)*16.
// ---------------------------------------------------------------------------
__global__ __launch_bounds__(256) void attn_combine(
    const float* __restrict__ Opart, const float* __restrict__ MLpart,
    const int* __restrict__ tix, u16* __restrict__ O1b)
{
  const int bq = blockIdx.x;
  const int bh = bq / 13, qb = bq % 13;
  const int tid = threadIdx.x;
  const int q = tid >> 2, dq = (tid & 3) * 16;
  const int rglob = qb * 64 + q;
  if (rglob >= TOPU) return;
  const int rowidx = tix[bh * TOPU + rglob];

  const size_t p0 = ((size_t)bq * 2 + 0) * 64 + q;
  const size_t p1 = ((size_t)bq * 2 + 1) * 64 + q;
  const float m0 = MLpart[p0 * 2], l0 = MLpart[p0 * 2 + 1];
  const float m1 = MLpart[p1 * 2], l1 = MLpart[p1 * 2 + 1];
  const float mx = fmaxf(m0, m1);
  const float c0 = __expf(m0 - mx), c1 = __expf(m1 - mx);
  const float linv = 1.0f / (l0 * c0 + l1 * c1);

  const int b = bh >> 4, h = bh & 15;
  u16* dst = O1b + (size_t)(b * LSEQ + rowidx) * DM + h * HD + dq;
  const float* o0 = Opart + p0 * 64 + dq;
  const float* o1 = Opart + p1 * 64 + dq;
  #pragma unroll
  for (int i = 0; i < 16; i += 4) {
    float4 a  = *reinterpret_cast<const float4*>(o0 + i);
    float4 bb = *reinterpret_cast<const float4*>(o1 + i);
    short4v o;
    o[0] = (short)f2bf((a.x * c0 + bb.x * c1) * linv);
    o[1] = (short)f2bf((a.y * c0 + bb.y * c1) * linv);
    o[2] = (short)f2bf((a.z * c0 + bb.z * c1) * linv);
    o[3] = (short)f2bf((a.w * c0 + bb.w * c1) * linv);
    *reinterpret_cast<short4v*>(dst + i) = o;
  }
}

// ---------------------------------------------------------------------------
extern "C" void kernel_launch(void* const* d_in, const int* in_sizes, int n_in,
                              void* d_out, int out_size, void* d_ws, size_t ws_size,
                              hipStream_t stream) {
  const float* x  = (const float*)d_in[0];
  const float* Wq = (const float*)d_in[1];
  const float* bq = (const float*)d_in[2];
  const float* Wk = (const float*)d_in[3];
  const float* bk = (const float*)d_in[4];
  const float* Wv = (const float*)d_in[5];
  const float* bv = (const float*)d_in[6];
  const float* Wo = (const float*)d_in[7];
  const float* bo = (const float*)d_in[8];
  float* out = (float*)d_out;

  char* w = (char*)d_ws;
  float* Qb = (float*)w;  w += (size_t)BHT * LSEQ * HD * 4;    // 32 MB fp32
  u16* x1   = (u16*)w;    w += (size_t)MROWS * DM * 2;         // 16 MB -> later Opart/MLpart
  u16* x2   = (u16*)w;    w += (size_t)MROWS * DM * 2;         // 16 MB -> later O1b
  u16* x3   = (u16*)w;    w += (size_t)MROWS * DM * 2;         // 16 MB -> later Kb
  u16* VgT  = (u16*)w;    w += (size_t)BHT * HD * LSEQ * 2;    // 16 MB (V^T)
  u16* Wkb  = (u16*)w;    w += (size_t)DM * DM * 2;            // 2 MB
  u16* Wvb  = (u16*)w;    w += (size_t)DM * DM * 2;
  u16* Wob  = (u16*)w;    w += (size_t)DM * DM * 2;
  u16* wq1  = (u16*)w;    w += (size_t)DM * DM * 2;            // -> later norms
  u16* wq2  = (u16*)w;    w += (size_t)DM * DM * 2;            // -> later tix
  u16* wq3  = (u16*)w;    w += (size_t)DM * DM * 2;

  u16*   O1b   = x2;
  u16*   Kb    = x3;
  float* norms = (float*)wq1;
  int*   tix   = (int*)wq2;
  // attn partials alias x1 (dead after K/V gemms): 13.6 MB + 0.43 MB <= 16 MB
  float* Opart  = (float*)x1;
  float* MLpart = Opart + (size_t)832 * 64 * 64;

  split3_kernel<<<4096, 256, 0, stream>>>(x,  x1,  x2,  x3,  MROWS * DM / 8);
  split3_kernel<<<512,  256, 0, stream>>>(Wq, wq1, wq2, wq3, DM * DM / 8);
  conv_bf16<<<512, 256, 0, stream>>>(Wk, Wkb, DM * DM / 8);
  conv_bf16<<<512, 256, 0, stream>>>(Wv, Wvb, DM * DM / 8);
  conv_bf16<<<512, 256, 0, stream>>>(Wo, Wob, DM * DM / 8);

  gemm_q_split<<<dim3(MROWS / 128, DM / 128), 256, 0, stream>>>(
      x1, x2, x3, wq1, wq2, wq3, bq, Qb);

  gemm_bf16<0><<<dim3(MROWS / 128, DM / 128), 256, 0, stream>>>(x1, Wkb, bk, (void*)Kb);
  gemm_bf16<2><<<dim3(MROWS / 128, DM / 128), 256, 0, stream>>>(x1, Wvb, bv, (void*)VgT);

  norms_kernel<<<BHT * LSEQ / 256, 256, 0, stream>>>(Qb, norms);
  select_topk<<<BHT, 1024, 0, stream>>>(norms, tix);

  hipMemsetAsync(O1b, 0, (size_t)MROWS * DM * 2, stream);

  attn_mfma<<<832, 256, 0, stream>>>(Qb, Kb, VgT, tix, Opart, MLpart);
  attn_combine<<<416, 256, 0, stream>>>(Opart, MLpart, tix, O1b);

  gemm_bf16<1><<<dim3(MROWS / 128, DM / 128), 256, 0, stream>>>(O1b, Wob, bo, (void*)out);
}

// Round 6
// 303.489 us; speedup vs baseline: 6.7740x; 1.0539x over previous
//
#include <hip/hip_runtime.h>
#include <cstddef>
#include <cstdint>

constexpr int LSEQ = 4096;
constexpr int DM   = 1024;
constexpr int HD   = 64;
constexpr int BHT  = 32;     // B*H
constexpr int TOPU = 819;
constexpr int MROWS = 8192;  // B*L

typedef unsigned short u16;
typedef __attribute__((ext_vector_type(8))) short short8v;  // 8 bf16 (4 VGPR)
typedef __attribute__((ext_vector_type(4))) short short4v;  // 4 bf16 (8B)
typedef __attribute__((ext_vector_type(4))) float f32x4;

__device__ __forceinline__ u16 f2bf(float f) {
  uint32_t u = __float_as_uint(f);
  u += 0x7fffu + ((u >> 16) & 1u);   // RNE
  return (u16)(u >> 16);
}
__device__ __forceinline__ float bf2f(u16 h) {
  return __uint_as_float(((uint32_t)h) << 16);
}

// async 16B global -> LDS (DMA).  LDS dest wave-uniform base; HW adds lane*16.
__device__ __forceinline__ void gl16(const void* g, void* l) {
  __builtin_amdgcn_global_load_lds(
      (const __attribute__((address_space(1))) void*)g,
      (__attribute__((address_space(3))) void*)l, 16, 0, 0);
}

// Inverse of the LDS swizzle e = (R*32 + C*8) ^ ((R&7)<<3) for linear slot S
// (u16 units): gives the (row R, k-granule C) whose data lives at slot S.
__device__ __forceinline__ void inv_swz(int S, int& R, int& C) {
  const int R0 = ((S >> 5) ^ (S >> 7)) & 1;
  const int R1 = (S >> 6) & 1;
  R = ((S >> 6) << 1) | R0;
  C = (((S >> 3) & 1) ^ R0) | ((((S >> 4) & 1) ^ R1) << 1);
}

// ---------------------------------------------------------------------------
// Fused prep: split3(x), split3(Wq), conv(Wk), conv(Wv), conv(Wo) in one pass.
// ---------------------------------------------------------------------------
__device__ __forceinline__ void split3_body(const float* src, u16* p1, u16* p2,
                                            u16* p3, int i) {
  const float4 a = *reinterpret_cast<const float4*>(src + (size_t)i * 8);
  const float4 b = *reinterpret_cast<const float4*>(src + (size_t)i * 8 + 4);
  float e[8] = {a.x, a.y, a.z, a.w, b.x, b.y, b.z, b.w};
  short8v v1, v2, v3;
  #pragma unroll
  for (int j = 0; j < 8; ++j) {
    u16 h1 = f2bf(e[j]);        float r1 = e[j] - bf2f(h1);
    u16 h2 = f2bf(r1);          float r2 = r1 - bf2f(h2);
    u16 h3 = f2bf(r2);
    v1[j] = (short)h1; v2[j] = (short)h2; v3[j] = (short)h3;
  }
  *reinterpret_cast<short8v*>(p1 + (size_t)i * 8) = v1;
  *reinterpret_cast<short8v*>(p2 + (size_t)i * 8) = v2;
  *reinterpret_cast<short8v*>(p3 + (size_t)i * 8) = v3;
}

__device__ __forceinline__ void conv_body(const float* src, u16* dst, int i) {
  const float4 a = *reinterpret_cast<const float4*>(src + (size_t)i * 8);
  const float4 b = *reinterpret_cast<const float4*>(src + (size_t)i * 8 + 4);
  short8v v;
  v[0] = (short)f2bf(a.x); v[1] = (short)f2bf(a.y);
  v[2] = (short)f2bf(a.z); v[3] = (short)f2bf(a.w);
  v[4] = (short)f2bf(b.x); v[5] = (short)f2bf(b.y);
  v[6] = (short)f2bf(b.z); v[7] = (short)f2bf(b.w);
  *reinterpret_cast<short8v*>(dst + (size_t)i * 8) = v;
}

__global__ __launch_bounds__(256) void prep_all(
    const float* __restrict__ x,  const float* __restrict__ Wq,
    const float* __restrict__ Wk, const float* __restrict__ Wv,
    const float* __restrict__ Wo,
    u16* __restrict__ x1, u16* __restrict__ x2, u16* __restrict__ x3,
    u16* __restrict__ wq1, u16* __restrict__ wq2, u16* __restrict__ wq3,
    u16* __restrict__ Wkb, u16* __restrict__ Wvb, u16* __restrict__ Wob)
{
  const int NX = MROWS * DM / 8;   // 1048576
  const int NW = DM * DM / 8;      // 131072
  int i = blockIdx.x * 256 + threadIdx.x;
  if (i < NX)                { split3_body(x,  x1,  x2,  x3,  i); return; }
  i -= NX;
  if (i < NW)                { split3_body(Wq, wq1, wq2, wq3, i); return; }
  i -= NW;
  if (i < NW)                { conv_body(Wk, Wkb, i); return; }
  i -= NW;
  if (i < NW)                { conv_body(Wv, Wvb, i); return; }
  i -= NW;
  if (i < NW)                { conv_body(Wo, Wob, i); }
}

// ---------------------------------------------------------------------------
// Q projection at fp32 accuracy via 3-piece split-bf16 MFMA (6 products).
// 128x128 tile, BK=32, 4 waves; global_load_lds staging (linear dest,
// inverse-swizzled source); fp32 output split-head; FUSED per-row norms
// (each wave covers one head's 64 cols for its 64 rows -> in-wave reduce).
// ---------------------------------------------------------------------------
__global__ __launch_bounds__(256) void gemm_q_split(
    const u16* __restrict__ X1, const u16* __restrict__ X2, const u16* __restrict__ X3,
    const u16* __restrict__ W1, const u16* __restrict__ W2, const u16* __restrict__ W3,
    const float* __restrict__ bias, float* __restrict__ Y,
    float* __restrict__ norms)
{
  __shared__ u16 As[3][128 * 32];
  __shared__ u16 Bs[3][128 * 32];
  const int tid = threadIdx.x;
  const int m0 = blockIdx.x * 128, n0 = blockIdx.y * 128;
  const int wid = tid >> 6, lane = tid & 63;
  const int wr = (wid >> 1) * 64, wc = (wid & 1) * 64;
  const int c = lane & 15, G = lane >> 4;

  int Rr[2], Cr[2];
  #pragma unroll
  for (int rr = 0; rr < 2; ++rr) inv_swz((tid + rr * 256) * 8, Rr[rr], Cr[rr]);

  f32x4 acc[4][4];
  #pragma unroll
  for (int mt = 0; mt < 4; ++mt)
    #pragma unroll
    for (int nt = 0; nt < 4; ++nt)
      acc[mt][nt] = (f32x4){0.f, 0.f, 0.f, 0.f};

  for (int k0 = 0; k0 < DM; k0 += 32) {
    #pragma unroll
    for (int rr = 0; rr < 2; ++rr) {
      const size_t goA = (size_t)(m0 + Rr[rr]) * DM + k0 + Cr[rr] * 8;
      const size_t goB = (size_t)(n0 + Rr[rr]) * DM + k0 + Cr[rr] * 8;
      const int lb = wid * 512 + rr * 2048;
      gl16(X1 + goA, &As[0][lb]);
      gl16(X2 + goA, &As[1][lb]);
      gl16(X3 + goA, &As[2][lb]);
      gl16(W1 + goB, &Bs[0][lb]);
      gl16(W2 + goB, &Bs[1][lb]);
      gl16(W3 + goB, &Bs[2][lb]);
    }
    __syncthreads();

    short8v bf[3][4];
    #pragma unroll
    for (int nt = 0; nt < 4; ++nt) {
      const int n = wc + nt * 16 + c;
      const int eo = (n * 32 + G * 8) ^ ((n & 7) << 3);
      bf[0][nt] = *reinterpret_cast<const short8v*>(&Bs[0][eo]);
      bf[1][nt] = *reinterpret_cast<const short8v*>(&Bs[1][eo]);
      bf[2][nt] = *reinterpret_cast<const short8v*>(&Bs[2][eo]);
    }
    #pragma unroll
    for (int mt = 0; mt < 4; ++mt) {
      const int m = wr + mt * 16 + c;
      const int eo = (m * 32 + G * 8) ^ ((m & 7) << 3);
      short8v a1 = *reinterpret_cast<const short8v*>(&As[0][eo]);
      short8v a2 = *reinterpret_cast<const short8v*>(&As[1][eo]);
      short8v a3 = *reinterpret_cast<const short8v*>(&As[2][eo]);
      #pragma unroll
      for (int nt = 0; nt < 4; ++nt) {
        acc[mt][nt] = __builtin_amdgcn_mfma_f32_16x16x32_bf16(a1, bf[0][nt], acc[mt][nt], 0, 0, 0);
        acc[mt][nt] = __builtin_amdgcn_mfma_f32_16x16x32_bf16(a1, bf[1][nt], acc[mt][nt], 0, 0, 0);
        acc[mt][nt] = __builtin_amdgcn_mfma_f32_16x16x32_bf16(a2, bf[0][nt], acc[mt][nt], 0, 0, 0);
        acc[mt][nt] = __builtin_amdgcn_mfma_f32_16x16x32_bf16(a2, bf[1][nt], acc[mt][nt], 0, 0, 0);
        acc[mt][nt] = __builtin_amdgcn_mfma_f32_16x16x32_bf16(a1, bf[2][nt], acc[mt][nt], 0, 0, 0);
        acc[mt][nt] = __builtin_amdgcn_mfma_f32_16x16x32_bf16(a3, bf[0][nt], acc[mt][nt], 0, 0, 0);
      }
    }
    __syncthreads();
  }

  float bb[4];
  #pragma unroll
  for (int nt = 0; nt < 4; ++nt) bb[nt] = bias[n0 + wc + nt * 16 + c];

  float ns[4][4];
  #pragma unroll
  for (int mt = 0; mt < 4; ++mt)
    #pragma unroll
    for (int r = 0; r < 4; ++r) ns[mt][r] = 0.f;

  #pragma unroll
  for (int mt = 0; mt < 4; ++mt) {
    #pragma unroll
    for (int nt = 0; nt < 4; ++nt) {
      const int n = n0 + wc + nt * 16 + c;
      const int h = n >> 6, d = n & 63;
      #pragma unroll
      for (int r = 0; r < 4; ++r) {
        const int m = m0 + wr + mt * 16 + G * 4 + r;
        const int b = m >> 12, l = m & (LSEQ - 1);
        const float val = acc[mt][nt][r] + bb[nt];
        Y[((size_t)((b << 4) + h) * LSEQ + l) * HD + d] = val;
        ns[mt][r] = fmaf(val, val, ns[mt][r]);
      }
    }
  }
  // in-wave reduce over the 16 c-lanes (covers all 64 cols of this head)
  #pragma unroll
  for (int mt = 0; mt < 4; ++mt)
    #pragma unroll
    for (int r = 0; r < 4; ++r) {
      float v = ns[mt][r];
      v += __shfl_xor(v, 1); v += __shfl_xor(v, 2);
      v += __shfl_xor(v, 4); v += __shfl_xor(v, 8);
      ns[mt][r] = v;
    }
  if (c == 0) {
    const int h = (n0 + wc) >> 6;
    #pragma unroll
    for (int mt = 0; mt < 4; ++mt)
      #pragma unroll
      for (int r = 0; r < 4; ++r) {
        const int m = m0 + wr + mt * 16 + G * 4 + r;
        const int b = m >> 12, l = m & (LSEQ - 1);
        norms[(((size_t)((b << 4) + h)) << 12) + l] = ns[mt][r];
      }
  }
}

// ---------------------------------------------------------------------------
// Fused K+V projection: grid (64, 16).  y<8 -> K (split-head bf16 out),
// y>=8 -> V (transposed per-head [bh*64+d][4096] out via LDS-staged T).
// LDS union: staging As/Bs (16KB) | transpose T (34.8KB).
// ---------------------------------------------------------------------------
__global__ __launch_bounds__(256) void gemm_kv(
    const u16* __restrict__ Xb, const u16* __restrict__ Wkb, const u16* __restrict__ Wvb,
    const float* __restrict__ bkp, const float* __restrict__ bvp,
    u16* __restrict__ Kb, u16* __restrict__ VgT)
{
  __shared__ u16 smem[128 * 136];      // 34816 B union
  u16* As = smem;
  u16* Bs = smem + 4096;
  const int tid = threadIdx.x;
  const bool isV = blockIdx.y >= 8;
  const int m0 = blockIdx.x * 128, n0 = (blockIdx.y & 7) * 128;
  const u16* Wb = isV ? Wvb : Wkb;
  const float* bias = isV ? bvp : bkp;
  const int wid = tid >> 6, lane = tid & 63;
  const int wr = (wid >> 1) * 64, wc = (wid & 1) * 64;
  const int c = lane & 15, G = lane >> 4;

  int Rr[2], Cr[2];
  #pragma unroll
  for (int rr = 0; rr < 2; ++rr) inv_swz((tid + rr * 256) * 8, Rr[rr], Cr[rr]);

  f32x4 acc[4][4];
  #pragma unroll
  for (int mt = 0; mt < 4; ++mt)
    #pragma unroll
    for (int nt = 0; nt < 4; ++nt)
      acc[mt][nt] = (f32x4){0.f, 0.f, 0.f, 0.f};

  for (int k0 = 0; k0 < DM; k0 += 32) {
    #pragma unroll
    for (int rr = 0; rr < 2; ++rr) {
      const size_t goA = (size_t)(m0 + Rr[rr]) * DM + k0 + Cr[rr] * 8;
      const size_t goB = (size_t)(n0 + Rr[rr]) * DM + k0 + Cr[rr] * 8;
      const int lb = wid * 512 + rr * 2048;
      gl16(Xb + goA, As + lb);
      gl16(Wb + goB, Bs + lb);
    }
    __syncthreads();

    short8v af[4], bf[4];
    #pragma unroll
    for (int mt = 0; mt < 4; ++mt) {
      const int m = wr + mt * 16 + c;
      af[mt] = *reinterpret_cast<const short8v*>(As + ((m * 32 + G * 8) ^ ((m & 7) << 3)));
      const int n = wc + mt * 16 + c;
      bf[mt] = *reinterpret_cast<const short8v*>(Bs + ((n * 32 + G * 8) ^ ((n & 7) << 3)));
    }
    #pragma unroll
    for (int mt = 0; mt < 4; ++mt)
      #pragma unroll
      for (int nt = 0; nt < 4; ++nt)
        acc[mt][nt] = __builtin_amdgcn_mfma_f32_16x16x32_bf16(af[mt], bf[nt], acc[mt][nt], 0, 0, 0);
    __syncthreads();
  }

  float bb[4];
  #pragma unroll
  for (int nt = 0; nt < 4; ++nt) bb[nt] = bias[n0 + wc + nt * 16 + c];

  if (isV) {
    // stage transposed in LDS (T[n][m_local], stride 136), then coalesced out
    #pragma unroll
    for (int mt = 0; mt < 4; ++mt) {
      #pragma unroll
      for (int nt = 0; nt < 4; ++nt) {
        const int n = wc + nt * 16 + c;
        const int mloc = wr + mt * 16 + G * 4;
        short4v pv;
        #pragma unroll
        for (int r = 0; r < 4; ++r) pv[r] = (short)f2bf(acc[mt][nt][r] + bb[nt]);
        *reinterpret_cast<short4v*>(smem + n * 136 + mloc) = pv;
      }
    }
    __syncthreads();
    const int bb2 = m0 >> 12;
    const int ml0 = m0 & (LSEQ - 1);
    #pragma unroll
    for (int uu = 0; uu < 8; ++uu) {
      const int u = uu * 256 + tid;
      const int n = u >> 4, kg = u & 15;
      short8v vvv = *reinterpret_cast<const short8v*>(smem + n * 136 + kg * 8);
      const int h = (n0 + n) >> 6, d = (n0 + n) & 63;
      *reinterpret_cast<short8v*>(
          VgT + ((size_t)((bb2 << 4) + h) * HD + d) * LSEQ + ml0 + kg * 8) = vvv;
    }
  } else {
    #pragma unroll
    for (int mt = 0; mt < 4; ++mt) {
      #pragma unroll
      for (int nt = 0; nt < 4; ++nt) {
        const int n = n0 + wc + nt * 16 + c;
        const int h = n >> 6, d = n & 63;
        #pragma unroll
        for (int r = 0; r < 4; ++r) {
          const int m = m0 + wr + mt * 16 + G * 4 + r;
          const int b = m >> 12, l = m & (LSEQ - 1);
          Kb[((size_t)((b << 4) + h) * LSEQ + l) * HD + d] = f2bf(acc[mt][nt][r] + bb[nt]);
        }
      }
    }
  }
}

// ---------------------------------------------------------------------------
// Output GEMM: out = O1b(bf16) @ Wob^T + bo, fp32 row-major out.
// ---------------------------------------------------------------------------
__global__ __launch_bounds__(256) void gemm_out(
    const u16* __restrict__ Xb, const u16* __restrict__ Wb,
    const float* __restrict__ bias, float* __restrict__ Y)
{
  __shared__ u16 As[128 * 32];
  __shared__ u16 Bs[128 * 32];
  const int tid = threadIdx.x;
  const int m0 = blockIdx.x * 128, n0 = blockIdx.y * 128;
  const int wid = tid >> 6, lane = tid & 63;
  const int wr = (wid >> 1) * 64, wc = (wid & 1) * 64;
  const int c = lane & 15, G = lane >> 4;

  int Rr[2], Cr[2];
  #pragma unroll
  for (int rr = 0; rr < 2; ++rr) inv_swz((tid + rr * 256) * 8, Rr[rr], Cr[rr]);

  f32x4 acc[4][4];
  #pragma unroll
  for (int mt = 0; mt < 4; ++mt)
    #pragma unroll
    for (int nt = 0; nt < 4; ++nt)
      acc[mt][nt] = (f32x4){0.f, 0.f, 0.f, 0.f};

  for (int k0 = 0; k0 < DM; k0 += 32) {
    #pragma unroll
    for (int rr = 0; rr < 2; ++rr) {
      const size_t goA = (size_t)(m0 + Rr[rr]) * DM + k0 + Cr[rr] * 8;
      const size_t goB = (size_t)(n0 + Rr[rr]) * DM + k0 + Cr[rr] * 8;
      const int lb = wid * 512 + rr * 2048;
      gl16(Xb + goA, As + lb);
      gl16(Wb + goB, Bs + lb);
    }
    __syncthreads();

    short8v af[4], bf[4];
    #pragma unroll
    for (int mt = 0; mt < 4; ++mt) {
      const int m = wr + mt * 16 + c;
      af[mt] = *reinterpret_cast<const short8v*>(As + ((m * 32 + G * 8) ^ ((m & 7) << 3)));
      const int n = wc + mt * 16 + c;
      bf[mt] = *reinterpret_cast<const short8v*>(Bs + ((n * 32 + G * 8) ^ ((n & 7) << 3)));
    }
    #pragma unroll
    for (int mt = 0; mt < 4; ++mt)
      #pragma unroll
      for (int nt = 0; nt < 4; ++nt)
        acc[mt][nt] = __builtin_amdgcn_mfma_f32_16x16x32_bf16(af[mt], bf[nt], acc[mt][nt], 0, 0, 0);
    __syncthreads();
  }

  float bb[4];
  #pragma unroll
  for (int nt = 0; nt < 4; ++nt) bb[nt] = bias[n0 + wc + nt * 16 + c];

  #pragma unroll
  for (int mt = 0; mt < 4; ++mt) {
    #pragma unroll
    for (int nt = 0; nt < 4; ++nt) {
      const int n = n0 + wc + nt * 16 + c;
      #pragma unroll
      for (int r = 0; r < 4; ++r) {
        const int m = m0 + wr + mt * 16 + G * 4 + r;
        Y[(size_t)m * DM + n] = acc[mt][nt][r] + bb[nt];
      }
    }
  }
}

// ---------------------------------------------------------------------------
// Per-bh top-TOPU selection (set only) -- byte-radix select + stable compact.
// ---------------------------------------------------------------------------
__global__ __launch_bounds__(1024) void select_topk(
    const float* __restrict__ norms, int* __restrict__ top_idx)
{
  __shared__ unsigned int keys[LSEQ];
  __shared__ unsigned int hist[256];
  __shared__ unsigned int wsums[16];
  __shared__ unsigned int sh_b, sh_above;

  const int tid = threadIdx.x;
  const int bh = blockIdx.x;

  for (int l = tid; l < LSEQ; l += 1024)
    keys[l] = __float_as_uint(norms[bh * LSEQ + l]);
  __syncthreads();

  unsigned int prefix = 0, rem = TOPU, total_gt = 0;
  for (int shift = 24; shift >= 0; shift -= 8) {
    if (tid < 256) hist[tid] = 0;
    __syncthreads();
    for (int l = tid; l < LSEQ; l += 1024) {
      const unsigned int k = keys[l];
      const bool in = (shift == 24) || ((k >> (shift + 8)) == prefix);
      if (in) atomicAdd(&hist[(k >> shift) & 255], 1);
    }
    __syncthreads();
    if (tid == 0) {
      unsigned int cum = 0; int b = 255;
      for (; b > 0; --b) {
        const unsigned int h = hist[b];
        if (cum + h >= rem) break;
        cum += h;
      }
      sh_b = (unsigned int)b; sh_above = cum;
    }
    __syncthreads();
    prefix = (prefix << 8) | sh_b;
    total_gt += sh_above;
    rem -= sh_above;
    __syncthreads();
  }
  const unsigned int T = prefix;

  const int lane = tid & 63, wv = tid >> 6;
  const int l0 = tid * 4;

  {
    unsigned int flags = 0; int cnt = 0;
    #pragma unroll
    for (int j = 0; j < 4; ++j)
      if (keys[l0 + j] > T) { flags |= 1u << j; ++cnt; }
    int incl = cnt;
    #pragma unroll
    for (int off = 1; off < 64; off <<= 1) {
      int nv = __shfl_up(incl, off);
      if (lane >= off) incl += nv;
    }
    if (lane == 63) wsums[wv] = (unsigned int)incl;
    __syncthreads();
    if (tid == 0) {
      unsigned int run = 0;
      for (int w = 0; w < 16; ++w) { unsigned int t = wsums[w]; wsums[w] = run; run += t; }
    }
    __syncthreads();
    unsigned int pos = wsums[wv] + (unsigned int)(incl - cnt);
    #pragma unroll
    for (int j = 0; j < 4; ++j)
      if (flags & (1u << j)) top_idx[bh * TOPU + (pos++)] = l0 + j;
  }
  __syncthreads();

  {
    unsigned int flags = 0; int cnt = 0;
    #pragma unroll
    for (int j = 0; j < 4; ++j)
      if (keys[l0 + j] == T) { flags |= 1u << j; ++cnt; }
    int incl = cnt;
    #pragma unroll
    for (int off = 1; off < 64; off <<= 1) {
      int nv = __shfl_up(incl, off);
      if (lane >= off) incl += nv;
    }
    if (lane == 63) wsums[wv] = (unsigned int)incl;
    __syncthreads();
    if (tid == 0) {
      unsigned int run = 0;
      for (int w = 0; w < 16; ++w) { unsigned int t = wsums[w]; wsums[w] = run; run += t; }
    }
    __syncthreads();
    unsigned int r0 = wsums[wv] + (unsigned int)(incl - cnt);
    #pragma unroll
    for (int j = 0; j < 4; ++j)
      if (flags & (1u << j)) {
        if (r0 < rem) top_idx[bh * TOPU + total_gt + r0] = l0 + j;
        ++r0;
      }
  }
}

// ---------------------------------------------------------------------------
// MFMA flash attention, split-K x2, fp32 partials.  Staging now via
// global_load_lds with inverse-swizzled global sources (linear LDS dest).
// ---------------------------------------------------------------------------
__global__ __launch_bounds__(256) void attn_mfma(
    const float* __restrict__ Qf, const u16* __restrict__ Kg,
    const u16* __restrict__ VgT, const int* __restrict__ tix,
    float* __restrict__ Opart, float* __restrict__ MLpart)
{
  __shared__ u16 Kc[128 * 64];      // [key][d-granule ^ (key&7)]
  __shared__ u16 Vt[64 * 128];      // [d][k-granule ^ (d&7)]
  __shared__ u16 Pt[4][16 * 136];   // per-wave [q][k], stride 136

  const int tid = threadIdx.x;
  const int wid = tid >> 6, lane = tid & 63;
  const int c = lane & 15, G = lane >> 4;

  // XCD grouping: 832 = 8 xcd * 104; each xcd handles 4 bh entirely.
  const int l = blockIdx.x;
  const int grp = l >> 3;
  const int bh = (grp / 26) * 8 + (l & 7);
  const int rem = grp % 26;
  const int qb = rem >> 1, ks = rem & 1;

  const size_t bhL = (size_t)bh * LSEQ;
  const int rglob = qb * 64 + wid * 16 + c;
  const int rowidx = (rglob < TOPU) ? tix[bh * TOPU + rglob] : -1;

  short8v qf[2];
  #pragma unroll
  for (int kf = 0; kf < 2; ++kf) {
    if (rowidx >= 0) {
      const float* qp = Qf + (bhL + rowidx) * HD + kf * 32 + G * 8;
      const float4 x0 = *reinterpret_cast<const float4*>(qp);
      const float4 x1 = *reinterpret_cast<const float4*>(qp + 4);
      short8v v;
      v[0] = (short)f2bf(x0.x * 0.125f); v[1] = (short)f2bf(x0.y * 0.125f);
      v[2] = (short)f2bf(x0.z * 0.125f); v[3] = (short)f2bf(x0.w * 0.125f);
      v[4] = (short)f2bf(x1.x * 0.125f); v[5] = (short)f2bf(x1.y * 0.125f);
      v[6] = (short)f2bf(x1.z * 0.125f); v[7] = (short)f2bf(x1.w * 0.125f);
      qf[kf] = v;
    } else {
      short8v v;
      #pragma unroll
      for (int j = 0; j < 8; ++j) v[j] = 0;
      qf[kf] = v;
    }
  }

  float m = -1e30f, lsum = 0.f;
  f32x4 oacc[4];
  #pragma unroll
  for (int dt = 0; dt < 4; ++dt) oacc[dt] = (f32x4){0.f, 0.f, 0.f, 0.f};

  const int ko0 = ks * (LSEQ / 2);
  const int wbase = (tid & ~63) * 8;      // wave-uniform LDS slot base (u16)
  for (int t = 0; t < LSEQ / 256; ++t) {
    const int ko = ko0 + t * 128;
    #pragma unroll
    for (int uu = 0; uu < 4; ++uu) {
      const int S = (uu * 256 + tid) * 8;
      const int key = S >> 6, dgk = ((S >> 3) & 7) ^ (key & 7);
      gl16(Kg + (bhL + ko + key) * HD + dgk * 8, Kc + uu * 2048 + wbase);
      const int d = S >> 7, kgv = ((S >> 3) & 15) ^ (d & 7);
      gl16(VgT + ((size_t)bh * HD + d) * LSEQ + ko + kgv * 8, Vt + uu * 2048 + wbase);
    }
    __syncthreads();

    // swapped QK^T: sacc[kt] reg r = S[key = kt*16 + G*4 + r][q = c]
    f32x4 sacc[8];
    __builtin_amdgcn_s_setprio(1);
    #pragma unroll
    for (int kt = 0; kt < 8; ++kt) {
      const int key = kt * 16 + c;
      short8v kb0 = *reinterpret_cast<const short8v*>(
          Kc + key * 64 + (((0 + G) ^ (key & 7)) << 3));
      short8v kb1 = *reinterpret_cast<const short8v*>(
          Kc + key * 64 + (((4 + G) ^ (key & 7)) << 3));
      f32x4 s = (f32x4){0.f, 0.f, 0.f, 0.f};
      s = __builtin_amdgcn_mfma_f32_16x16x32_bf16(kb0, qf[0], s, 0, 0, 0);
      s = __builtin_amdgcn_mfma_f32_16x16x32_bf16(kb1, qf[1], s, 0, 0, 0);
      sacc[kt] = s;
    }
    __builtin_amdgcn_s_setprio(0);

    // online softmax: per lane, one q-row (q = c)
    float smax = -1e30f;
    #pragma unroll
    for (int kt = 0; kt < 8; ++kt) {
      float a0 = fmaxf(sacc[kt][0], sacc[kt][1]);
      float a1 = fmaxf(sacc[kt][2], sacc[kt][3]);
      smax = fmaxf(smax, fmaxf(a0, a1));
    }
    smax = fmaxf(smax, __shfl_xor(smax, 16));
    smax = fmaxf(smax, __shfl_xor(smax, 32));
    const float mnew = fmaxf(m, smax);
    const float corr = __expf(m - mnew);
    float ssum = 0.f;
    #pragma unroll
    for (int kt = 0; kt < 8; ++kt) {
      float p0 = __expf(sacc[kt][0] - mnew);
      float p1 = __expf(sacc[kt][1] - mnew);
      float p2 = __expf(sacc[kt][2] - mnew);
      float p3 = __expf(sacc[kt][3] - mnew);
      ssum += (p0 + p1) + (p2 + p3);
      short4v pv;
      pv[0] = (short)f2bf(p0); pv[1] = (short)f2bf(p1);
      pv[2] = (short)f2bf(p2); pv[3] = (short)f2bf(p3);
      *reinterpret_cast<short4v*>(&Pt[wid][c * 136 + kt * 16 + G * 4]) = pv;
    }
    ssum += __shfl_xor(ssum, 16);
    ssum += __shfl_xor(ssum, 32);
    lsum = lsum * corr + ssum;
    m = mnew;
    #pragma unroll
    for (int dt = 0; dt < 4; ++dt) oacc[dt] *= corr;

    // PV: O^T += V^T @ P
    __builtin_amdgcn_s_setprio(1);
    #pragma unroll
    for (int kf = 0; kf < 4; ++kf) {
      short8v pf = *reinterpret_cast<const short8v*>(
          &Pt[wid][c * 136 + kf * 32 + G * 8]);
      #pragma unroll
      for (int dt = 0; dt < 4; ++dt) {
        const int d = dt * 16 + c;
        short8v vf = *reinterpret_cast<const short8v*>(
            Vt + d * 128 + (((kf * 4 + G) ^ (d & 7)) << 3));
        oacc[dt] = __builtin_amdgcn_mfma_f32_16x16x32_bf16(vf, pf, oacc[dt], 0, 0, 0);
      }
    }
    __builtin_amdgcn_s_setprio(0);
    __syncthreads();
  }

  const int q = wid * 16 + c;
  const size_t pb = ((size_t)(bh * 13 + qb) * 2 + ks) * 64 + q;
  float* op = Opart + pb * 64;
  #pragma unroll
  for (int dt = 0; dt < 4; ++dt)
    *reinterpret_cast<f32x4*>(op + dt * 16 + G * 4) = oacc[dt];
  if (G == 0) {
    MLpart[pb * 2]     = m;
    MLpart[pb * 2 + 1] = lsum;
  }
}

// ---------------------------------------------------------------------------
// Flash split-K combine: O = (O0*c0 + O1*c1) / (l0*c0 + l1*c1), scatter bf16.
// ---------------------------------------------------------------------------
__global__ __launch_bounds__(256) void attn_combine(
    const float* __restrict__ Opart, const float* __restrict__ MLpart,
    const int* __restrict__ tix, u16* __restrict__ O1b)
{
  const int bq = blockIdx.x;
  const int bh = bq / 13, qb = bq % 13;
  const int tid = threadIdx.x;
  const int q = tid >> 2, dq = (tid & 3) * 16;
  const int rglob = qb * 64 + q;
  if (rglob >= TOPU) return;
  const int rowidx = tix[bh * TOPU + rglob];

  const size_t p0 = ((size_t)bq * 2 + 0) * 64 + q;
  const size_t p1 = ((size_t)bq * 2 + 1) * 64 + q;
  const float m0 = MLpart[p0 * 2], l0 = MLpart[p0 * 2 + 1];
  const float m1 = MLpart[p1 * 2], l1 = MLpart[p1 * 2 + 1];
  const float mx = fmaxf(m0, m1);
  const float c0 = __expf(m0 - mx), c1 = __expf(m1 - mx);
  const float linv = 1.0f / (l0 * c0 + l1 * c1);

  const int b = bh >> 4, h = bh & 15;
  u16* dst = O1b + (size_t)(b * LSEQ + rowidx) * DM + h * HD + dq;
  const float* o0 = Opart + p0 * 64 + dq;
  const float* o1 = Opart + p1 * 64 + dq;
  #pragma unroll
  for (int i = 0; i < 16; i += 4) {
    float4 a  = *reinterpret_cast<const float4*>(o0 + i);
    float4 bb = *reinterpret_cast<const float4*>(o1 + i);
    short4v o;
    o[0] = (short)f2bf((a.x * c0 + bb.x * c1) * linv);
    o[1] = (short)f2bf((a.y * c0 + bb.y * c1) * linv);
    o[2] = (short)f2bf((a.z * c0 + bb.z * c1) * linv);
    o[3] = (short)f2bf((a.w * c0 + bb.w * c1) * linv);
    *reinterpret_cast<short4v*>(dst + i) = o;
  }
}

// ---------------------------------------------------------------------------
extern "C" void kernel_launch(void* const* d_in, const int* in_sizes, int n_in,
                              void* d_out, int out_size, void* d_ws, size_t ws_size,
                              hipStream_t stream) {
  const float* x  = (const float*)d_in[0];
  const float* Wq = (const float*)d_in[1];
  const float* bq = (const float*)d_in[2];
  const float* Wk = (const float*)d_in[3];
  const float* bk = (const float*)d_in[4];
  const float* Wv = (const float*)d_in[5];
  const float* bv = (const float*)d_in[6];
  const float* Wo = (const float*)d_in[7];
  const float* bo = (const float*)d_in[8];
  float* out = (float*)d_out;

  char* w = (char*)d_ws;
  float* Qb = (float*)w;  w += (size_t)BHT * LSEQ * HD * 4;    // 32 MB fp32
  u16* x1   = (u16*)w;    w += (size_t)MROWS * DM * 2;         // 16 MB -> later Opart/MLpart
  u16* x2   = (u16*)w;    w += (size_t)MROWS * DM * 2;         // 16 MB -> later O1b
  u16* x3   = (u16*)w;    w += (size_t)MROWS * DM * 2;         // 16 MB -> later Kb
  u16* VgT  = (u16*)w;    w += (size_t)BHT * HD * LSEQ * 2;    // 16 MB (V^T)
  u16* Wkb  = (u16*)w;    w += (size_t)DM * DM * 2;            // 2 MB
  u16* Wvb  = (u16*)w;    w += (size_t)DM * DM * 2;
  u16* Wob  = (u16*)w;    w += (size_t)DM * DM * 2;
  u16* wq1  = (u16*)w;    w += (size_t)DM * DM * 2;
  u16* wq2  = (u16*)w;    w += (size_t)DM * DM * 2;            // -> later tix
  u16* wq3  = (u16*)w;    w += (size_t)DM * DM * 2;
  float* norms = (float*)w; w += (size_t)BHT * LSEQ * 4;       // 512 KB (separate!)

  u16*   O1b  = x2;
  u16*   Kb   = x3;
  int*   tix  = (int*)wq2;           // dead after gemm_q_split
  float* Opart  = (float*)x1;        // dead after gemm_kv
  float* MLpart = Opart + (size_t)832 * 64 * 64;

  prep_all<<<6144, 256, 0, stream>>>(x, Wq, Wk, Wv, Wo,
                                     x1, x2, x3, wq1, wq2, wq3, Wkb, Wvb, Wob);

  gemm_q_split<<<dim3(MROWS / 128, DM / 128), 256, 0, stream>>>(
      x1, x2, x3, wq1, wq2, wq3, bq, Qb, norms);

  gemm_kv<<<dim3(MROWS / 128, 16), 256, 0, stream>>>(x1, Wkb, Wvb, bk, bv, Kb, VgT);

  select_topk<<<BHT, 1024, 0, stream>>>(norms, tix);

  hipMemsetAsync(O1b, 0, (size_t)MROWS * DM * 2, stream);

  attn_mfma<<<832, 256, 0, stream>>>(Qb, Kb, VgT, tix, Opart, MLpart);
  attn_combine<<<416, 256, 0, stream>>>(Opart, MLpart, tix, O1b);

  gemm_out<<<dim3(MROWS / 128, DM / 128), 256, 0, stream>>>(O1b, Wob, bo, out);
}